// Round 10
// baseline (4892.965 us; speedup 1.0000x reference)
//
#include <hip/hip_runtime.h>
#include <hip/hip_cooperative_groups.h>
#include <cstdint>
#include <cstddef>

namespace cg = cooperative_groups;

#define BQ 4
#define NSEQ 8192
#define DIMC 512
#define NH 8
#define DH 64
#define NM 256
#define NITER 6
#define KW 33
#define BHN (BQ*NH)
#define NSLICE 16
#define JS (NSEQ/NSLICE)

typedef unsigned short bf16u;
typedef __attribute__((ext_vector_type(8))) short short8;
typedef __attribute__((ext_vector_type(4))) float f32x4;
#define MFMA16(a,b,c) __builtin_amdgcn_mfma_f32_16x16x32_bf16(a,b,c,0,0,0)

__device__ inline float b2f(bf16u u) { return __uint_as_float(((unsigned int)u) << 16); }
__device__ inline bf16u f2b(float f) {
  unsigned int u = __float_as_uint(f);
  unsigned int r = (u + 0x7fffu + ((u >> 16) & 1u)) >> 16;  // RNE
  return (bf16u)r;
}
// truncation split: v = hi + lo + O(2^-17 |v|)
__device__ inline void splt(float v, unsigned short& h, unsigned short& l) {
  unsigned u = __float_as_uint(v);
  h = (unsigned short)(u >> 16);
  float hf = __uint_as_float(u & 0xffff0000u);
  l = (unsigned short)(__float_as_uint(v - hf) >> 16);
}

__global__ __launch_bounds__(256) void k_fill(float* out, int n, float v) {
  int i = blockIdx.x * 256 + threadIdx.x;
  if (i < n) out[i] = v;
}

// ---------------- merged prep: x->bf16, w_qkv^T->bf16, w_out^T->bf16
__global__ __launch_bounds__(256) void c_prep(
    const float* __restrict__ x, const float* __restrict__ w_qkv, const float* __restrict__ w_out,
    bf16u* __restrict__ xb, bf16u* __restrict__ wqkvT, bf16u* __restrict__ woutT) {
  int id = blockIdx.x;
  if (id < 8192) {
    int i = id*256 + threadIdx.x;
    const float4* s = (const float4*)(x + (size_t)i*8);
    float4 a = s[0], b = s[1];
    ushort4 lo, hi;
    lo.x=f2b(a.x); lo.y=f2b(a.y); lo.z=f2b(a.z); lo.w=f2b(a.w);
    hi.x=f2b(b.x); hi.y=f2b(b.y); hi.z=f2b(b.z); hi.w=f2b(b.w);
    ushort4* d = (ushort4*)(xb + (size_t)i*8);
    d[0] = lo; d[1] = hi;
  } else if (id < 8192+3072) {
    int i = (id-8192)*256 + threadIdx.x;
    int r = i / 1536, c = i - r*1536;
    wqkvT[(size_t)c*DIMC + r] = f2b(w_qkv[i]);
  } else {
    int i = (id-11264)*256 + threadIdx.x;
    int r = i >> 9, c = i & 511;
    woutT[(size_t)c*DIMC + r] = f2b(w_out[i]);
  }
}

// ---------------- MFMA GEMM  C[M,-] = A[M,K](bf16) @ Bt[N,K]^T(bf16)
// reg-staged, padded LDS [72]; XCD-chunked block swizzle. (round-7 proven form)
template<int MODE>
__global__ __launch_bounds__(256) void k_mgemm(
    const bf16u* __restrict__ A, const bf16u* __restrict__ Bt, int K, int nb,
    bf16u* __restrict__ oq, bf16u* __restrict__ ok, bf16u* __restrict__ ovT,
    const float* __restrict__ bias, float* __restrict__ oC) {
  __shared__ short As[128][72];
  __shared__ short Bs[128][72];
  const int id = blockIdx.x;
  const int rid = (id & 7) * ((int)gridDim.x >> 3) + (id >> 3);
  const int m0 = (rid / nb) * 128, n0 = (rid % nb) * 128;
  const int t = threadIdx.x;
  const int wid = t>>6, l = t&63, lm = l&15, lg = l>>4;
  const int wr = (wid>>1)*64, wc = (wid&1)*64;
  f32x4 acc[4][4];
  #pragma unroll
  for (int i=0;i<4;++i)
    #pragma unroll
    for (int j=0;j<4;++j) acc[i][j] = (f32x4){0,0,0,0};
  for (int k0=0; k0<K; k0+=64) {
    #pragma unroll
    for (int i=0;i<4;++i) {
      int c = t + i*256;
      int row = c>>3, kc = (c&7)<<3;
      *(uint4*)&As[row][kc] = *(const uint4*)(A  + (size_t)(m0+row)*K + k0+kc);
      *(uint4*)&Bs[row][kc] = *(const uint4*)(Bt + (size_t)(n0+row)*K + k0+kc);
    }
    __syncthreads();
    #pragma unroll
    for (int ks=0;ks<2;++ks) {
      short8 af[4], bfr[4];
      #pragma unroll
      for (int i=0;i<4;++i) {
        af[i]  = *(const short8*)&As[wr+i*16+lm][ks*32+lg*8];
        bfr[i] = *(const short8*)&Bs[wc+i*16+lm][ks*32+lg*8];
      }
      #pragma unroll
      for (int i=0;i<4;++i)
        #pragma unroll
        for (int j=0;j<4;++j)
          acc[i][j] = MFMA16(af[i], bfr[j], acc[i][j]);
    }
    __syncthreads();
  }
  if (MODE==0) {
    #pragma unroll
    for (int mt=0;mt<4;++mt) {
      int grb = m0 + wr + mt*16 + lg*4;
      int b_ = grb>>13, nrow = grb & (NSEQ-1);
      #pragma unroll
      for (int nt=0;nt<4;++nt) {
        int gc = n0 + wc + nt*16 + lm;
        int which = gc>>9, h_ = (gc>>6)&7, d = gc&63;
        if (which==2) {
          ushort4 pk;
          pk.x=f2b(acc[mt][nt][0]); pk.y=f2b(acc[mt][nt][1]);
          pk.z=f2b(acc[mt][nt][2]); pk.w=f2b(acc[mt][nt][3]);
          *(ushort4*)(ovT + (((size_t)b_*NH+h_)*DH + d)*NSEQ + nrow) = pk;
        } else {
          bf16u* dst = (which==0) ? oq : ok;
          float mul = (which==0) ? 0.125f : 1.0f;
          #pragma unroll
          for (int r=0;r<4;++r)
            dst[(((size_t)b_*NH+h_)*NSEQ + nrow + r)*DH + d] = f2b(acc[mt][nt][r]*mul);
        }
      }
    }
  } else {
    #pragma unroll
    for (int mt=0;mt<4;++mt)
      #pragma unroll
      for (int r=0;r<4;++r) {
        int gr = m0 + wr + mt*16 + lg*4 + r;
        #pragma unroll
        for (int nt=0;nt<4;++nt) {
          int gc = n0 + wc + nt*16 + lm;
          oC[(size_t)gr*DIMC + gc] = acc[mt][nt][r] + bias[gc];
        }
      }
  }
}

// ---------------- landmark means over blocks of 32
__global__ __launch_bounds__(256) void k_landmarks(
    const bf16u* __restrict__ q, const bf16u* __restrict__ kbuf,
    float* __restrict__ ql, float* __restrict__ klm,
    bf16u* __restrict__ qlb, bf16u* __restrict__ klmb) {
  int gi = blockIdx.x*4 + (threadIdx.x>>6);
  int d = threadIdx.x & 63;
  int bh = gi >> 8, i = gi & 255;
  size_t srcoff = ((size_t)bh*NSEQ + (size_t)i*32)*DH + d;
  float sq = 0, sk = 0;
  #pragma unroll
  for (int j = 0; j < 32; ++j) {
    sq += b2f(q[srcoff + (size_t)j*DH]);
    sk += b2f(kbuf[srcoff + (size_t)j*DH]);
  }
  float mq = sq * (1.0f/32.0f), mk = sk * (1.0f/32.0f);
  ql[(size_t)gi*DH + d]  = mq;  klm[(size_t)gi*DH + d]  = mk;
  qlb[(size_t)gi*DH + d] = f2b(mq); klmb[(size_t)gi*DH + d] = f2b(mk);
}

// ---------------- split-bf16 MFMA GEMM for attn2: C = exp(A @ S^T), in-loader split
__global__ __launch_bounds__(256) void k_qlk_exp(
    const float* __restrict__ A, const float* __restrict__ S, float* __restrict__ C, int K) {
  __shared__ short Ah[128][40], Al[128][40], Bh[64][40], Bl[64][40];
  const int bh = blockIdx.y;
  const size_t abase = (size_t)bh*256*K;
  const size_t cbase = (size_t)bh<<16;
  const int m0 = (blockIdx.x & 1)*128, n0 = (blockIdx.x >> 1)*64;
  const int t = threadIdx.x;
  const int wid = t>>6, l = t&63, lm = l&15, lg = l>>4;
  const int wr = (wid&1)*64, wc = (wid>>1)*32;
  f32x4 acc[4][2];
  #pragma unroll
  for (int i=0;i<4;++i) { acc[i][0] = (f32x4){0,0,0,0}; acc[i][1] = (f32x4){0,0,0,0}; }
  for (int k0=0; k0<K; k0+=32) {
    #pragma unroll
    for (int i=0;i<4;++i) {
      int idx = t + i*256;
      int row = idx>>3, kc = (idx&7)<<2;
      float4 v = *(const float4*)(A + abase + (size_t)(m0+row)*K + k0+kc);
      ushort4 hh, ll;
      splt(v.x, hh.x, ll.x); splt(v.y, hh.y, ll.y);
      splt(v.z, hh.z, ll.z); splt(v.w, hh.w, ll.w);
      *(ushort4*)&Ah[row][kc] = hh; *(ushort4*)&Al[row][kc] = ll;
    }
    #pragma unroll
    for (int i=0;i<2;++i) {
      int idx = t + i*256;
      int row = idx>>3, kc = (idx&7)<<2;
      float4 v = *(const float4*)(S + abase + (size_t)(n0+row)*K + k0+kc);
      ushort4 hh, ll;
      splt(v.x, hh.x, ll.x); splt(v.y, hh.y, ll.y);
      splt(v.z, hh.z, ll.z); splt(v.w, hh.w, ll.w);
      *(ushort4*)&Bh[row][kc] = hh; *(ushort4*)&Bl[row][kc] = ll;
    }
    __syncthreads();
    short8 ah[4], al[4], sh[2], sl[2];
    #pragma unroll
    for (int mt=0;mt<4;++mt) {
      ah[mt] = *(const short8*)&Ah[wr+mt*16+lm][lg*8];
      al[mt] = *(const short8*)&Al[wr+mt*16+lm][lg*8];
    }
    #pragma unroll
    for (int nt=0;nt<2;++nt) {
      sh[nt] = *(const short8*)&Bh[wc+nt*16+lm][lg*8];
      sl[nt] = *(const short8*)&Bl[wc+nt*16+lm][lg*8];
    }
    #pragma unroll
    for (int mt=0;mt<4;++mt)
      #pragma unroll
      for (int nt=0;nt<2;++nt) {
        acc[mt][nt] = MFMA16(ah[mt], sh[nt], acc[mt][nt]);
        acc[mt][nt] = MFMA16(ah[mt], sl[nt], acc[mt][nt]);
        acc[mt][nt] = MFMA16(al[mt], sh[nt], acc[mt][nt]);
      }
    __syncthreads();
  }
  #pragma unroll
  for (int mt=0;mt<4;++mt)
    #pragma unroll
    for (int nt=0;nt<2;++nt)
      #pragma unroll
      for (int r=0;r<4;++r) {
        int gr = m0 + wr + mt*16 + lg*4 + r;
        int gc = n0 + wc + nt*16 + lm;
        C[cbase + (size_t)gr*256 + gc] = __expf(acc[mt][nt][r]);
      }
}

// ---------------- row softmax-normalize (+ zero scal, block 0)
__global__ __launch_bounds__(256) void k_rowsm(float* __restrict__ a2, unsigned* __restrict__ scal) {
  if (blockIdx.x == 0 && threadIdx.x < 2) scal[threadIdx.x] = 0u;
  int row = blockIdx.x*4 + (threadIdx.x>>6);
  int l = threadIdx.x & 63;
  float4* p = (float4*)(a2 + (size_t)row*256 + l*4);
  float4 v = *p;
  float s = v.x+v.y+v.z+v.w;
  #pragma unroll
  for (int d=1; d<64; d<<=1) s += __shfl_xor(s, d);
  float inv = 1.0f/s;
  v.x*=inv; v.y*=inv; v.z*=inv; v.w*=inv;
  *p = v;
}

// ---------------- pinv init reductions (coalesced; one block per bh)
__global__ __launch_bounds__(256) void k_pinv_reduce(const float* __restrict__ a2, unsigned* scal) {
  const int bh = blockIdx.x, t = threadIdx.x;
  const int wv = t>>6, lane = t&63;
  const float* A = a2 + (size_t)bh*NM*NM;
  // col sums: lane-per-column, coalesced
  float cs = 0;
  for (int r = 0; r < NM; ++r) cs += fabsf(A[(size_t)r*NM + t]);
  // row sums: wave wv handles rows wv*64..wv*64+63; float4 per lane + butterfly
  float rmax = 0;
  for (int i = 0; i < 64; ++i) {
    int r = wv*64 + i;
    float4 v = *(const float4*)(A + (size_t)r*NM + lane*4);
    float s = fabsf(v.x)+fabsf(v.y)+fabsf(v.z)+fabsf(v.w);
    #pragma unroll
    for (int d=1; d<64; d<<=1) s += __shfl_xor(s, d);
    rmax = fmaxf(rmax, s);
  }
  __shared__ float red[256];
  red[t] = cs; __syncthreads();
  for (int s2 = 128; s2 > 0; s2 >>= 1) { if (t < s2) red[t] = fmaxf(red[t], red[t+s2]); __syncthreads(); }
  if (t == 0) atomicMax(scal+1, __float_as_uint(red[0]));
  __syncthreads();
  red[t] = rmax; __syncthreads();
  for (int s2 = 128; s2 > 0; s2 >>= 1) { if (t < s2) red[t] = fmaxf(red[t], red[t+s2]); __syncthreads(); }
  if (t == 0) atomicMax(scal+0, __float_as_uint(red[0]));
}

// ---------------- split a2 -> hi/lo planes; zc = a2^T/c -> hi/lo planes (LDS transpose)
__global__ __launch_bounds__(256) void k_split_init(
    const float* __restrict__ a2, const unsigned* __restrict__ scal,
    bf16u* __restrict__ a2h, bf16u* __restrict__ a2l,
    bf16u* __restrict__ zch, bf16u* __restrict__ zcl) {
  __shared__ bf16u Th[64][72], Tl[64][72];
  const int bh = blockIdx.y;
  const int tx = blockIdx.x & 3, ty = blockIdx.x >> 2;
  const int r0 = ty*64, c0 = tx*64;
  const size_t base = (size_t)bh<<16;
  const int t = threadIdx.x;
  const float rc = 1.0f/(__uint_as_float(scal[0]) * __uint_as_float(scal[1]));
  {
    int rr = t>>2, cc0 = (t&3)*16;
    const float* src = a2 + base + (size_t)(r0+rr)*256 + c0+cc0;
    bf16u hbuf[16], lbuf[16];
    #pragma unroll
    for (int u=0;u<4;++u) {
      float4 v = *(const float4*)(src + u*4);
      float vv[4] = {v.x,v.y,v.z,v.w};
      #pragma unroll
      for (int e=0;e<4;++e) {
        splt(vv[e], hbuf[u*4+e], lbuf[u*4+e]);
        bf16u zh_, zl_;
        splt(vv[e]*rc, zh_, zl_);
        Th[cc0+u*4+e][rr] = zh_;
        Tl[cc0+u*4+e][rr] = zl_;
      }
    }
    bf16u* dh = a2h + base + (size_t)(r0+rr)*256 + c0+cc0;
    bf16u* dl = a2l + base + (size_t)(r0+rr)*256 + c0+cc0;
    #pragma unroll
    for (int u=0;u<4;++u) {
      *(ushort4*)(dh + u*4) = *(ushort4*)&hbuf[u*4];
      *(ushort4*)(dl + u*4) = *(ushort4*)&lbuf[u*4];
    }
  }
  __syncthreads();
  {
    int cc = t>>2, rr0 = (t&3)*16;
    bf16u* dh = zch + base + (size_t)(c0+cc)*256 + r0+rr0;
    bf16u* dl = zcl + base + (size_t)(c0+cc)*256 + r0+rr0;
    #pragma unroll
    for (int u=0;u<4;++u) {
      *(ushort4*)(dh + u*4) = *(ushort4*)&Th[cc][rr0+u*4];
      *(ushort4*)(dl + u*4) = *(ushort4*)&Tl[cc][rr0+u*4];
    }
  }
}

// ---------------- cooperative fused Newton-Schulz chain (13 GEMM steps, 1 launch)
struct NsLds { short Ah[64][36]; short Al[64][36]; short Bh[64][36]; short Bl[64][36]; };

__device__ __forceinline__ void ns_gemm64(
    NsLds& S, const bf16u* pAh, const bf16u* pAl, const bf16u* pBh, const bf16u* pBl,
    size_t base, int m0, int n0, int t, int lm, int lg, int wc, f32x4* acc) {
  const int row = t>>2, kc = (t&3)<<3;
  for (int k0=0; k0<256; k0+=32) {
    *(uint4*)&S.Ah[row][kc] = *(const uint4*)(pAh + base + (size_t)(m0+row)*256 + k0+kc);
    *(uint4*)&S.Al[row][kc] = *(const uint4*)(pAl + base + (size_t)(m0+row)*256 + k0+kc);
    *(uint4*)&S.Bh[row][kc] = *(const uint4*)(pBh + base + (size_t)(n0+row)*256 + k0+kc);
    *(uint4*)&S.Bl[row][kc] = *(const uint4*)(pBl + base + (size_t)(n0+row)*256 + k0+kc);
    __syncthreads();
    short8 sh = *(const short8*)&S.Bh[wc+lm][lg*8];
    short8 sl = *(const short8*)&S.Bl[wc+lm][lg*8];
    #pragma unroll
    for (int mt=0;mt<4;++mt) {
      short8 ah = *(const short8*)&S.Ah[mt*16+lm][lg*8];
      short8 al = *(const short8*)&S.Al[mt*16+lm][lg*8];
      acc[mt] = MFMA16(ah, sh, acc[mt]);
      acc[mt] = MFMA16(ah, sl, acc[mt]);
      acc[mt] = MFMA16(al, sh, acc[mt]);
    }
    __syncthreads();
  }
}

__global__ __launch_bounds__(256, 4) void k_ns_coop(
    bf16u* a2h, bf16u* a2l, bf16u* s1h, bf16u* s1l,
    bf16u* cmh, bf16u* cml, bf16u* wh, bf16u* wl,
    bf16u* zch, bf16u* zcl, const unsigned* scal) {
  cg::grid_group g = cg::this_grid();
  __shared__ NsLds S;
  const int t = threadIdx.x;
  const int l = t&63, lm = l&15, lg = l>>4;
  const int wid = t>>6, wc = wid*16;
  const int job = blockIdx.x;
  const int zj = job >> 9;                 // 0..1
  const int rem = job & 511;
  const int bh = rem >> 4, tile = rem & 15;
  const int m0 = (tile&3)*64, n0 = (tile>>2)*64;
  const size_t base = (size_t)bh<<16;
  bf16u* c1h = a2h; bf16u* c1l = a2l;      // a2 planes dead after step 0
  f32x4 acc[4];

  auto epi = [&](int phase) {
    float rc = (phase==0) ? 1.0f/(__uint_as_float(scal[0])*__uint_as_float(scal[1])) : 1.0f;
    #pragma unroll
    for (int mt=0;mt<4;++mt)
      #pragma unroll
      for (int r=0;r<4;++r) {
        int gr = m0 + mt*16 + lg*4 + r;
        int gc = n0 + wc + lm;
        size_t idx = base + (size_t)gr*256 + gc;
        float a = acc[mt][r];
        bf16u hh, ll;
        if (phase==0) {                    // w0 = a2@a2^T * rc
          splt(a*rc, hh, ll); wh[idx]=hh; wl[idx]=ll;
        } else if (phase==1) {             // s1 = w@w ; cm = 15I - 7w + s1
          splt(a, hh, ll); s1h[idx]=hh; s1l[idx]=ll;
          float wv2 = b2f(wh[idx]) + b2f(wl[idx]);
          float cb = ((gr==gc)?15.0f:0.0f) - 7.0f*wv2 + a;
          splt(cb, hh, ll); cmh[idx]=hh; cml[idx]=ll;
        } else if (phase==2) {             // c1 = z@w
          splt(a, hh, ll); c1h[idx]=hh; c1l[idx]=ll;
        } else if (phase==3) {             // w' = 3.25w - 0.25*(s1@cm)
          float xv = b2f(wh[idx]) + b2f(wl[idx]);
          splt(3.25f*xv - 0.25f*a, hh, ll); wh[idx]=hh; wl[idx]=ll;
        } else {                           // z' = 3.25z - 0.25*(c1@cm)
          float xv = b2f(zch[idx]) + b2f(zcl[idx]);
          splt(3.25f*xv - 0.25f*a, hh, ll); zch[idx]=hh; zcl[idx]=ll;
        }
      }
  };

  // step 0: w0 (512 jobs)
  #pragma unroll
  for (int i=0;i<4;++i) acc[i] = (f32x4){0,0,0,0};
  if (zj == 0) { ns_gemm64(S, a2h,a2l, a2h,a2l, base,m0,n0,t,lm,lg,wc, acc); epi(0); }
  __threadfence();
  g.sync();
  for (int it = 0; it < NITER; ++it) {
    // phase 1: z0 -> s1+cm ; z1 -> c1   (1024 jobs)
    #pragma unroll
    for (int i=0;i<4;++i) acc[i] = (f32x4){0,0,0,0};
    if (zj == 0) { ns_gemm64(S, wh,wl, wh,wl, base,m0,n0,t,lm,lg,wc, acc); epi(1); }
    else         { ns_gemm64(S, zch,zcl, wh,wl, base,m0,n0,t,lm,lg,wc, acc); epi(2); }
    __threadfence();
    g.sync();
    // phase 2: z0 -> w update ; z1 -> z update (last iter: z only)
    #pragma unroll
    for (int i=0;i<4;++i) acc[i] = (f32x4){0,0,0,0};
    if (it == NITER-1) {
      if (zj == 1) { ns_gemm64(S, c1h,c1l, cmh,cml, base,m0,n0,t,lm,lg,wc, acc); epi(4); }
    } else {
      if (zj == 0) { ns_gemm64(S, s1h,s1l, cmh,cml, base,m0,n0,t,lm,lg,wc, acc); epi(3); }
      else         { ns_gemm64(S, c1h,c1l, cmh,cml, base,m0,n0,t,lm,lg,wc, acc); epi(4); }
    }
    __threadfence();
    g.sync();
  }
}

// ---------------- fused MFMA flash attention (no max-subtraction), reg-staged padded
template<int MODE>
__global__ __launch_bounds__(256) void k_flash(
    const bf16u* __restrict__ qg, const bf16u* __restrict__ kg,
    const bf16u* __restrict__ vtg, float* __restrict__ fpart, bf16u* __restrict__ outb) {
  constexpr int NCH = (MODE==0) ? (JS/64) : 4;
  const int bh = blockIdx.y;
  const int tile = blockIdx.x;
  const int t = threadIdx.x;
  const int wid = t>>6, l = t&63, lm = l&15, lg = l>>4;
  const size_t NQbase = (MODE==0) ? ((size_t)bh*NM) : ((size_t)bh*NSEQ + (size_t)tile*256);
  const int NJ = (MODE==0) ? NSEQ : NM;
  const int j0base = (MODE==0) ? tile*JS : 0;

  __shared__ short Ks[64][72];
  __shared__ short Vs[64][72];
  __shared__ short Pt[4][64][72];

  short8 qf[4][2];
  {
    const bf16u* qrow = qg + (NQbase + (size_t)wid*64) * DH;
    #pragma unroll
    for (int mt=0;mt<4;++mt)
      #pragma unroll
      for (int ks=0;ks<2;++ks)
        qf[mt][ks] = *(const short8*)(qrow + (size_t)(mt*16+lm)*DH + ks*32 + lg*8);
  }
  f32x4 oacc[4][4];
  #pragma unroll
  for (int i=0;i<4;++i)
    #pragma unroll
    for (int j=0;j<4;++j) oacc[i][j] = (f32x4){0,0,0,0};
  float rs[4][4];
  #pragma unroll
  for (int i=0;i<4;++i) { rs[i][0]=0; rs[i][1]=0; rs[i][2]=0; rs[i][3]=0; }

  const bf16u* kbh = kg  + (size_t)bh*NJ*DH;
  const bf16u* vbh = vtg + (size_t)bh*DH*NJ;

  for (int ch=0; ch<NCH; ++ch) {
    int j0 = j0base + ch*64;
    #pragma unroll
    for (int i=0;i<2;++i) {
      int c = t + i*256;
      int row = c>>3, kc = (c&7)<<3;
      *(uint4*)&Ks[row][kc] = *(const uint4*)(kbh + (size_t)(j0+row)*DH + kc);
      *(uint4*)&Vs[row][kc] = *(const uint4*)(vbh + (size_t)row*NJ + j0 + kc);
    }
    __syncthreads();
    short8 kf[4][2];
    #pragma unroll
    for (int jt=0;jt<4;++jt)
      #pragma unroll
      for (int ks=0;ks<2;++ks)
        kf[jt][ks] = *(const short8*)&Ks[jt*16+lm][ks*32+lg*8];
    #pragma unroll
    for (int mt=0;mt<4;++mt) {
      #pragma unroll
      for (int jt=0;jt<4;++jt) {
        f32x4 s = (f32x4){0,0,0,0};
        s = MFMA16(qf[mt][0], kf[jt][0], s);
        s = MFMA16(qf[mt][1], kf[jt][1], s);
        #pragma unroll
        for (int r=0;r<4;++r) {
          float p = __expf(s[r]);
          rs[mt][r] += p;
          Pt[wid][mt*16+lg*4+r][jt*16+lm] = f2b(p);
        }
      }
    }
    short8 vf[4][2];
    #pragma unroll
    for (int dt=0;dt<4;++dt)
      #pragma unroll
      for (int jw=0;jw<2;++jw)
        vf[dt][jw] = *(const short8*)&Vs[dt*16+lm][jw*32+lg*8];
    #pragma unroll
    for (int mt=0;mt<4;++mt) {
      short8 pa0 = *(const short8*)&Pt[wid][mt*16+lm][lg*8];
      short8 pa1 = *(const short8*)&Pt[wid][mt*16+lm][32+lg*8];
      #pragma unroll
      for (int dt=0;dt<4;++dt) {
        oacc[mt][dt] = MFMA16(pa0, vf[dt][0], oacc[mt][dt]);
        oacc[mt][dt] = MFMA16(pa1, vf[dt][1], oacc[mt][dt]);
      }
    }
    __syncthreads();
  }
  #pragma unroll
  for (int mt=0;mt<4;++mt)
    #pragma unroll
    for (int r=0;r<4;++r) {
      float v = rs[mt][r];
      v += __shfl_xor(v, 1); v += __shfl_xor(v, 2);
      v += __shfl_xor(v, 4); v += __shfl_xor(v, 8);
      rs[mt][r] = v;
    }
  if (MODE==0) {
    float* fb = fpart + (((size_t)bh*NSLICE + tile)*NM)*65;
    #pragma unroll
    for (int mt=0;mt<4;++mt)
      #pragma unroll
      for (int r=0;r<4;++r) {
        int row = wid*64 + mt*16 + lg*4 + r;
        float* fr = fb + (size_t)row*65;
        #pragma unroll
        for (int dt=0;dt<4;++dt) fr[dt*16+lm] = oacc[mt][dt][r];
        if (lm==0) fr[64] = rs[mt][r];
      }
  } else {
    const int b_ = bh>>3, h_ = bh&7;
    #pragma unroll
    for (int mt=0;mt<4;++mt)
      #pragma unroll
      for (int r=0;r<4;++r) {
        float inv = 1.0f/rs[mt][r];
        int n = tile*256 + wid*64 + mt*16 + lg*4 + r;
        bf16u* orow = outb + ((size_t)b_*NSEQ + n)*DIMC + h_*DH;
        #pragma unroll
        for (int dt=0;dt<4;++dt)
          orow[dt*16+lm] = f2b(oacc[mt][dt][r]*inv);
      }
  }
}

// combine -> w1T fp32 [bh][64][256]
__global__ __launch_bounds__(256) void k_attn3v_combine(
    const float* __restrict__ fpart, float* __restrict__ w1T) {
  int gi = blockIdx.x*4 + (threadIdx.x>>6);
  int d = threadIdx.x & 63;
  int bh = gi >> 8, i = gi & 255;
  float accd = 0, ssum = 0;
  #pragma unroll
  for (int s = 0; s < NSLICE; ++s) {
    const float* fp = fpart + (((size_t)bh*NSLICE + s)*NM + i)*65;
    accd += fp[d];
    ssum += fp[64];
  }
  w1T[((size_t)bh*64 + d)*256 + i] = accd / ssum;
}

// ---------------- w2T[bh][64][256] = w1T @ z^T  (z planes pre-split; A split in-loader)
__global__ __launch_bounds__(256) void k_w2nat(
    const float* __restrict__ w1T, const bf16u* __restrict__ zh, const bf16u* __restrict__ zl,
    bf16u* __restrict__ w2T) {
  __shared__ short Ah[64][36], Al[64][36], Bh[64][36], Bl[64][36];
  const int bh = blockIdx.y;
  const int n0 = blockIdx.x*64;
  const size_t a0 = (size_t)bh*64*256;
  const size_t s0 = (size_t)bh<<16;
  const int t = threadIdx.x;
  const int wid = t>>6, l = t&63, lm = l&15, lg = l>>4;
  const int wc = wid*16;
  f32x4 acc[4];
  #pragma unroll
  for (int i=0;i<4;++i) acc[i] = (f32x4){0,0,0,0};
  for (int k0=0; k0<256; k0+=32) {
    #pragma unroll
    for (int i=0;i<2;++i) {
      int idx = t + i*256;
      int row = idx>>3, kc = (idx&7)<<2;
      float4 v = *(const float4*)(w1T + a0 + (size_t)row*256 + k0+kc);
      ushort4 hh, ll;
      splt(v.x, hh.x, ll.x); splt(v.y, hh.y, ll.y);
      splt(v.z, hh.z, ll.z); splt(v.w, hh.w, ll.w);
      *(ushort4*)&Ah[row][kc] = hh; *(ushort4*)&Al[row][kc] = ll;
    }
    {
      int row = t>>2, ch = (t&3)<<3;
      *(uint4*)&Bh[row][ch] = *(const uint4*)(zh + s0 + (size_t)(n0+row)*256 + k0+ch);
      *(uint4*)&Bl[row][ch] = *(const uint4*)(zl + s0 + (size_t)(n0+row)*256 + k0+ch);
    }
    __syncthreads();
    short8 sh = *(const short8*)&Bh[wc+lm][lg*8];
    short8 sl = *(const short8*)&Bl[wc+lm][lg*8];
    #pragma unroll
    for (int mt=0;mt<4;++mt) {
      short8 ah = *(const short8*)&Ah[mt*16+lm][lg*8];
      short8 al = *(const short8*)&Al[mt*16+lm][lg*8];
      acc[mt] = MFMA16(ah, sh, acc[mt]);
      acc[mt] = MFMA16(ah, sl, acc[mt]);
      acc[mt] = MFMA16(al, sh, acc[mt]);
    }
    __syncthreads();
  }
  #pragma unroll
  for (int mt=0;mt<4;++mt)
    #pragma unroll
    for (int r=0;r<4;++r) {
      int gm = mt*16 + lg*4 + r;
      w2T[a0 + (size_t)gm*256 + n0 + wc + lm] = f2b(acc[mt][r]);
    }
}

// ---------------- depthwise conv residual from vT, LDS-transposed staging
__global__ __launch_bounds__(256) void k_conv_add(
    const bf16u* __restrict__ vt, const float* __restrict__ wc, bf16u* __restrict__ outb) {
  __shared__ short Vs[288][72];
  __shared__ float Wsh[40];
  const int bh = blockIdx.y, n0 = blockIdx.x*256;
  const int b_ = bh>>3, h_ = bh&7;
  const int t = threadIdx.x;
  if (t < KW) Wsh[t] = wc[h_*KW + t];
  const bf16u* vrow = vt + (size_t)bh*DH*NSEQ;
  {
    int d = t&63, seg = t>>6;
    #pragma unroll
    for (int u=0; u<9; ++u) {
      int nl = seg*72 + u*8;
      int gn = n0 - 16 + nl;
      bf16u e8[8];
      if (gn >= 0 && gn + 8 <= NSEQ) {
        *(uint4*)e8 = *(const uint4*)(vrow + (size_t)d*NSEQ + gn);
      } else {
        #pragma unroll
        for (int e=0;e<8;++e) {
          int g = gn + e;
          e8[e] = (g>=0 && g<NSEQ) ? vrow[(size_t)d*NSEQ + g] : (bf16u)0;
        }
      }
      #pragma unroll
      for (int e=0;e<8;++e) Vs[nl+e][d] = e8[e];
    }
  }
  __syncthreads();
  const int d = t&63, q = t>>6;
  #pragma unroll
  for (int c2=0;c2<4;++c2) {
    int nb = q*64 + c2*16;
    float wv[48];
    #pragma unroll
    for (int i=0;i<48;++i) wv[i] = b2f(Vs[nb+i][d]);
    #pragma unroll
    for (int e=0;e<16;++e) {
      float s = 0;
      #pragma unroll
      for (int k=0;k<KW;++k) s = fmaf(wv[e+k], Wsh[k], s);
      size_t oi = ((size_t)b_*NSEQ + n0 + nb + e)*DIMC + h_*DH + d;
      outb[oi] = f2b(b2f(outb[oi]) + s);
    }
  }
}

extern "C" void kernel_launch(void* const* d_in, const int* in_sizes, int n_in,
                              void* d_out, int out_size, void* d_ws, size_t ws_size,
                              hipStream_t stream) {
  (void)in_sizes; (void)n_in;
  const float* x      = (const float*)d_in[0];
  const float* w_qkv  = (const float*)d_in[1];
  const float* w_out  = (const float*)d_in[2];
  const float* b_out  = (const float*)d_in[3];
  const float* w_conv = (const float*)d_in[4];
  float* out = (float*)d_out;

  const size_t QKV_E = (size_t)BHN*NSEQ*DH;   // 16,777,216
  const size_t LM_E  = (size_t)BHN*NM*DH;     // 524,288
  const size_t MM_E  = (size_t)BHN*NM*NM;     // 2,097,152
  const size_t PLSZ  = MM_E*2;                // one bf16 plane = 4 MiB

  char* p = (char*)d_ws;
  char* nsb   = p;          p += 9*PLSZ;      // 36 MiB: NS planes P0..P7 + spare (fpart 34.1)
  bf16u* zch  = (bf16u*)p;  p += PLSZ;
  bf16u* zcl  = (bf16u*)p;  p += PLSZ;
  bf16u* qb    = (bf16u*)p; p += QKV_E*2;
  bf16u* kb    = (bf16u*)p; p += QKV_E*2;     // (-> outb)
  bf16u* vT    = (bf16u*)p; p += QKV_E*2;
  bf16u* wqkvT = (bf16u*)p; p += (size_t)DIMC*3*DIMC*2;
  bf16u* woutT = (bf16u*)p; p += (size_t)DIMC*DIMC*2;
  float* ql    = (float*)p; p += LM_E*4;
  float* klm   = (float*)p; p += LM_E*4;
  bf16u* qlb   = (bf16u*)p; p += LM_E*2;
  bf16u* klmb  = (bf16u*)p; p += LM_E*2;
  float* w1T   = (float*)p; p += LM_E*4;
  bf16u* w2T   = (bf16u*)p; p += LM_E*2;
  unsigned* scal = (unsigned*)p; p += 256;
  size_t need = (size_t)(p - (char*)d_ws);

  if (ws_size < need) {
    k_fill<<<(out_size + 255)/256, 256, 0, stream>>>(out, out_size, 12345.0f);
    return;
  }

  bf16u* a2h  = (bf16u*)(nsb + 0*PLSZ);
  bf16u* a2l  = (bf16u*)(nsb + 1*PLSZ);
  bf16u* s1h  = (bf16u*)(nsb + 2*PLSZ);
  bf16u* s1l  = (bf16u*)(nsb + 3*PLSZ);
  bf16u* cmh  = (bf16u*)(nsb + 4*PLSZ);
  bf16u* cml  = (bf16u*)(nsb + 5*PLSZ);
  bf16u* wh   = (bf16u*)(nsb + 6*PLSZ);
  bf16u* wl   = (bf16u*)(nsb + 7*PLSZ);
  float* a2f  = (float*)(nsb + 2*PLSZ);
  float* fpart = (float*)nsb;
  bf16u* xb  = (bf16u*)nsb;

  // 1. converts
  c_prep<<<12288, 256, 0, stream>>>(x, w_qkv, w_out, xb, wqkvT, woutT);
  // 2. qkv projection (MFMA, XCD-chunked swizzle)
  k_mgemm<0><<<3072, 256, 0, stream>>>(xb, wqkvT, DIMC, 12, qb, kb, vT, nullptr, nullptr);
  // 3. landmarks
  k_landmarks<<<(BHN*NM)/4, 256, 0, stream>>>(qb, kb, ql, klm, qlb, klmb);
  // 4. attn2 = softmax(ql@klm^T)
  k_qlk_exp<<<dim3(8, BHN), 256, 0, stream>>>(ql, klm, a2f, DH);
  k_rowsm<<<BHN*NM/4, 256, 0, stream>>>(a2f, scal);
  // 5. pinv init
  k_pinv_reduce<<<BHN, 256, 0, stream>>>(a2f, scal);
  k_split_init<<<dim3(16, BHN), 256, 0, stream>>>(a2f, scal, a2h, a2l, zch, zcl);
  // 6. fused Newton-Schulz chain (single cooperative launch)
  {
    void* kargs[] = { (void*)&a2h, (void*)&a2l, (void*)&s1h, (void*)&s1l,
                      (void*)&cmh, (void*)&cml, (void*)&wh,  (void*)&wl,
                      (void*)&zch, (void*)&zcl, (void*)&scal };
    hipLaunchCooperativeKernel((const void*)k_ns_coop, dim3(1024), dim3(256),
                               kargs, 0, stream);
  }
  // 7. w1 = softmax(ql@k^T)@v (MFMA flash, 16 slices) -> w1T
  k_flash<0><<<dim3(NSLICE, BHN), 256, 0, stream>>>(qlb, kb, vT, fpart, nullptr);
  k_attn3v_combine<<<(BHN*NM)/4, 256, 0, stream>>>(fpart, w1T);
  // 8. w2T = w1T @ z^T
  k_w2nat<<<dim3(4, BHN), 256, 0, stream>>>(w1T, zch, zcl, w2T);
  // 9. attn1 @ w2 -> outb (MFMA flash)
  bf16u* outb = kb;
  k_flash<1><<<dim3(NSEQ/256, BHN), 256, 0, stream>>>(qb, klmb, w2T, nullptr, outb);
  // 10. conv residual
  k_conv_add<<<dim3(NSEQ/256, BHN), 256, 0, stream>>>(vT, w_conv, outb);
  // 11. output projection
  k_mgemm<1><<<1024, 256, 0, stream>>>(outb, woutT, DIMC, 4, nullptr, nullptr, nullptr, b_out, out);
}

// Round 11
// 695.971 us; speedup vs baseline: 7.0304x; 7.0304x over previous
//
#include <hip/hip_runtime.h>
#include <cstdint>
#include <cstddef>

#define BQ 4
#define NSEQ 8192
#define DIMC 512
#define NH 8
#define DH 64
#define NM 256
#define NITER 6
#define KW 33
#define BHN (BQ*NH)
#define NSLICE 16
#define JS (NSEQ/NSLICE)

typedef unsigned short bf16u;
typedef __attribute__((ext_vector_type(8))) short short8;
typedef __attribute__((ext_vector_type(4))) float f32x4;
#define MFMA16(a,b,c) __builtin_amdgcn_mfma_f32_16x16x32_bf16(a,b,c,0,0,0)

__device__ inline float b2f(bf16u u) { return __uint_as_float(((unsigned int)u) << 16); }
__device__ inline bf16u f2b(float f) {
  unsigned int u = __float_as_uint(f);
  unsigned int r = (u + 0x7fffu + ((u >> 16) & 1u)) >> 16;  // RNE
  return (bf16u)r;
}
// truncation split: v = hi + lo + O(2^-17 |v|)
__device__ inline void splt(float v, unsigned short& h, unsigned short& l) {
  unsigned u = __float_as_uint(v);
  h = (unsigned short)(u >> 16);
  float hf = __uint_as_float(u & 0xffff0000u);
  l = (unsigned short)(__float_as_uint(v - hf) >> 16);
}

__global__ __launch_bounds__(256) void k_fill(float* out, int n, float v) {
  int i = blockIdx.x * 256 + threadIdx.x;
  if (i < n) out[i] = v;
}

// ---------------- merged prep: x->bf16, w_qkv^T->bf16, w_out^T->bf16
__global__ __launch_bounds__(256) void c_prep(
    const float* __restrict__ x, const float* __restrict__ w_qkv, const float* __restrict__ w_out,
    bf16u* __restrict__ xb, bf16u* __restrict__ wqkvT, bf16u* __restrict__ woutT) {
  int id = blockIdx.x;
  if (id < 8192) {
    int i = id*256 + threadIdx.x;
    const float4* s = (const float4*)(x + (size_t)i*8);
    float4 a = s[0], b = s[1];
    ushort4 lo, hi;
    lo.x=f2b(a.x); lo.y=f2b(a.y); lo.z=f2b(a.z); lo.w=f2b(a.w);
    hi.x=f2b(b.x); hi.y=f2b(b.y); hi.z=f2b(b.z); hi.w=f2b(b.w);
    ushort4* d = (ushort4*)(xb + (size_t)i*8);
    d[0] = lo; d[1] = hi;
  } else if (id < 8192+3072) {
    int i = (id-8192)*256 + threadIdx.x;
    int r = i / 1536, c = i - r*1536;
    wqkvT[(size_t)c*DIMC + r] = f2b(w_qkv[i]);
  } else {
    int i = (id-11264)*256 + threadIdx.x;
    int r = i >> 9, c = i & 511;
    woutT[(size_t)c*DIMC + r] = f2b(w_out[i]);
  }
}

// ---------------- MFMA GEMM  C[M,-] = A[M,K](bf16) @ Bt[N,K]^T(bf16)
// reg-staged, padded LDS [72]; XCD-chunked block swizzle. (round-7 proven form)
template<int MODE>
__global__ __launch_bounds__(256) void k_mgemm(
    const bf16u* __restrict__ A, const bf16u* __restrict__ Bt, int K, int nb,
    bf16u* __restrict__ oq, bf16u* __restrict__ ok, bf16u* __restrict__ ovT,
    const float* __restrict__ bias, float* __restrict__ oC) {
  __shared__ short As[128][72];
  __shared__ short Bs[128][72];
  const int id = blockIdx.x;
  const int rid = (id & 7) * ((int)gridDim.x >> 3) + (id >> 3);
  const int m0 = (rid / nb) * 128, n0 = (rid % nb) * 128;
  const int t = threadIdx.x;
  const int wid = t>>6, l = t&63, lm = l&15, lg = l>>4;
  const int wr = (wid>>1)*64, wc = (wid&1)*64;
  f32x4 acc[4][4];
  #pragma unroll
  for (int i=0;i<4;++i)
    #pragma unroll
    for (int j=0;j<4;++j) acc[i][j] = (f32x4){0,0,0,0};
  for (int k0=0; k0<K; k0+=64) {
    #pragma unroll
    for (int i=0;i<4;++i) {
      int c = t + i*256;
      int row = c>>3, kc = (c&7)<<3;
      *(uint4*)&As[row][kc] = *(const uint4*)(A  + (size_t)(m0+row)*K + k0+kc);
      *(uint4*)&Bs[row][kc] = *(const uint4*)(Bt + (size_t)(n0+row)*K + k0+kc);
    }
    __syncthreads();
    #pragma unroll
    for (int ks=0;ks<2;++ks) {
      short8 af[4], bfr[4];
      #pragma unroll
      for (int i=0;i<4;++i) {
        af[i]  = *(const short8*)&As[wr+i*16+lm][ks*32+lg*8];
        bfr[i] = *(const short8*)&Bs[wc+i*16+lm][ks*32+lg*8];
      }
      #pragma unroll
      for (int i=0;i<4;++i)
        #pragma unroll
        for (int j=0;j<4;++j)
          acc[i][j] = MFMA16(af[i], bfr[j], acc[i][j]);
    }
    __syncthreads();
  }
  if (MODE==0) {
    #pragma unroll
    for (int mt=0;mt<4;++mt) {
      int grb = m0 + wr + mt*16 + lg*4;
      int b_ = grb>>13, nrow = grb & (NSEQ-1);
      #pragma unroll
      for (int nt=0;nt<4;++nt) {
        int gc = n0 + wc + nt*16 + lm;
        int which = gc>>9, h_ = (gc>>6)&7, d = gc&63;
        if (which==2) {
          ushort4 pk;
          pk.x=f2b(acc[mt][nt][0]); pk.y=f2b(acc[mt][nt][1]);
          pk.z=f2b(acc[mt][nt][2]); pk.w=f2b(acc[mt][nt][3]);
          *(ushort4*)(ovT + (((size_t)b_*NH+h_)*DH + d)*NSEQ + nrow) = pk;
        } else {
          bf16u* dst = (which==0) ? oq : ok;
          float mul = (which==0) ? 0.125f : 1.0f;
          #pragma unroll
          for (int r=0;r<4;++r)
            dst[(((size_t)b_*NH+h_)*NSEQ + nrow + r)*DH + d] = f2b(acc[mt][nt][r]*mul);
        }
      }
    }
  } else {
    #pragma unroll
    for (int mt=0;mt<4;++mt)
      #pragma unroll
      for (int r=0;r<4;++r) {
        int gr = m0 + wr + mt*16 + lg*4 + r;
        #pragma unroll
        for (int nt=0;nt<4;++nt) {
          int gc = n0 + wc + nt*16 + lm;
          oC[(size_t)gr*DIMC + gc] = acc[mt][nt][r] + bias[gc];
        }
      }
  }
}

// ---------------- landmark means over blocks of 32
__global__ __launch_bounds__(256) void k_landmarks(
    const bf16u* __restrict__ q, const bf16u* __restrict__ kbuf,
    float* __restrict__ ql, float* __restrict__ klm,
    bf16u* __restrict__ qlb, bf16u* __restrict__ klmb) {
  int gi = blockIdx.x*4 + (threadIdx.x>>6);
  int d = threadIdx.x & 63;
  int bh = gi >> 8, i = gi & 255;
  size_t srcoff = ((size_t)bh*NSEQ + (size_t)i*32)*DH + d;
  float sq = 0, sk = 0;
  #pragma unroll
  for (int j = 0; j < 32; ++j) {
    sq += b2f(q[srcoff + (size_t)j*DH]);
    sk += b2f(kbuf[srcoff + (size_t)j*DH]);
  }
  float mq = sq * (1.0f/32.0f), mk = sk * (1.0f/32.0f);
  ql[(size_t)gi*DH + d]  = mq;  klm[(size_t)gi*DH + d]  = mk;
  qlb[(size_t)gi*DH + d] = f2b(mq); klmb[(size_t)gi*DH + d] = f2b(mk);
}

// ---------------- split-bf16 MFMA GEMM for attn2: C = exp(A @ S^T), in-loader split
__global__ __launch_bounds__(256) void k_qlk_exp(
    const float* __restrict__ A, const float* __restrict__ S, float* __restrict__ C, int K) {
  __shared__ short Ah[128][40], Al[128][40], Bh[64][40], Bl[64][40];
  const int bh = blockIdx.y;
  const size_t abase = (size_t)bh*256*K;
  const size_t cbase = (size_t)bh<<16;
  const int m0 = (blockIdx.x & 1)*128, n0 = (blockIdx.x >> 1)*64;
  const int t = threadIdx.x;
  const int wid = t>>6, l = t&63, lm = l&15, lg = l>>4;
  const int wr = (wid&1)*64, wc = (wid>>1)*32;
  f32x4 acc[4][2];
  #pragma unroll
  for (int i=0;i<4;++i) { acc[i][0] = (f32x4){0,0,0,0}; acc[i][1] = (f32x4){0,0,0,0}; }
  for (int k0=0; k0<K; k0+=32) {
    #pragma unroll
    for (int i=0;i<4;++i) {
      int idx = t + i*256;
      int row = idx>>3, kc = (idx&7)<<2;
      float4 v = *(const float4*)(A + abase + (size_t)(m0+row)*K + k0+kc);
      ushort4 hh, ll;
      splt(v.x, hh.x, ll.x); splt(v.y, hh.y, ll.y);
      splt(v.z, hh.z, ll.z); splt(v.w, hh.w, ll.w);
      *(ushort4*)&Ah[row][kc] = hh; *(ushort4*)&Al[row][kc] = ll;
    }
    #pragma unroll
    for (int i=0;i<2;++i) {
      int idx = t + i*256;
      int row = idx>>3, kc = (idx&7)<<2;
      float4 v = *(const float4*)(S + abase + (size_t)(n0+row)*K + k0+kc);
      ushort4 hh, ll;
      splt(v.x, hh.x, ll.x); splt(v.y, hh.y, ll.y);
      splt(v.z, hh.z, ll.z); splt(v.w, hh.w, ll.w);
      *(ushort4*)&Bh[row][kc] = hh; *(ushort4*)&Bl[row][kc] = ll;
    }
    __syncthreads();
    short8 ah[4], al[4], sh[2], sl[2];
    #pragma unroll
    for (int mt=0;mt<4;++mt) {
      ah[mt] = *(const short8*)&Ah[wr+mt*16+lm][lg*8];
      al[mt] = *(const short8*)&Al[wr+mt*16+lm][lg*8];
    }
    #pragma unroll
    for (int nt=0;nt<2;++nt) {
      sh[nt] = *(const short8*)&Bh[wc+nt*16+lm][lg*8];
      sl[nt] = *(const short8*)&Bl[wc+nt*16+lm][lg*8];
    }
    #pragma unroll
    for (int mt=0;mt<4;++mt)
      #pragma unroll
      for (int nt=0;nt<2;++nt) {
        acc[mt][nt] = MFMA16(ah[mt], sh[nt], acc[mt][nt]);
        acc[mt][nt] = MFMA16(ah[mt], sl[nt], acc[mt][nt]);
        acc[mt][nt] = MFMA16(al[mt], sh[nt], acc[mt][nt]);
      }
    __syncthreads();
  }
  #pragma unroll
  for (int mt=0;mt<4;++mt)
    #pragma unroll
    for (int nt=0;nt<2;++nt)
      #pragma unroll
      for (int r=0;r<4;++r) {
        int gr = m0 + wr + mt*16 + lg*4 + r;
        int gc = n0 + wc + nt*16 + lm;
        C[cbase + (size_t)gr*256 + gc] = __expf(acc[mt][nt][r]);
      }
}

// ---------------- row softmax-normalize (+ zero scal, block 0)
__global__ __launch_bounds__(256) void k_rowsm(float* __restrict__ a2, unsigned* __restrict__ scal) {
  if (blockIdx.x == 0 && threadIdx.x < 2) scal[threadIdx.x] = 0u;
  int row = blockIdx.x*4 + (threadIdx.x>>6);
  int l = threadIdx.x & 63;
  float4* p = (float4*)(a2 + (size_t)row*256 + l*4);
  float4 v = *p;
  float s = v.x+v.y+v.z+v.w;
  #pragma unroll
  for (int d=1; d<64; d<<=1) s += __shfl_xor(s, d);
  float inv = 1.0f/s;
  v.x*=inv; v.y*=inv; v.z*=inv; v.w*=inv;
  *p = v;
}

// ---------------- pinv init reductions (coalesced; one block per bh)
__global__ __launch_bounds__(256) void k_pinv_reduce(const float* __restrict__ a2, unsigned* scal) {
  const int bh = blockIdx.x, t = threadIdx.x;
  const int wv = t>>6, lane = t&63;
  const float* A = a2 + (size_t)bh*NM*NM;
  // col sums: lane-per-column, coalesced
  float cs = 0;
  for (int r = 0; r < NM; ++r) cs += fabsf(A[(size_t)r*NM + t]);
  // row sums: wave wv handles rows wv*64..wv*64+63; float4 per lane + butterfly
  float rmax = 0;
  for (int i = 0; i < 64; ++i) {
    int r = wv*64 + i;
    float4 v = *(const float4*)(A + (size_t)r*NM + lane*4);
    float s = fabsf(v.x)+fabsf(v.y)+fabsf(v.z)+fabsf(v.w);
    #pragma unroll
    for (int d=1; d<64; d<<=1) s += __shfl_xor(s, d);
    rmax = fmaxf(rmax, s);
  }
  __shared__ float red[256];
  red[t] = cs; __syncthreads();
  for (int s2 = 128; s2 > 0; s2 >>= 1) { if (t < s2) red[t] = fmaxf(red[t], red[t+s2]); __syncthreads(); }
  if (t == 0) atomicMax(scal+1, __float_as_uint(red[0]));
  __syncthreads();
  red[t] = rmax; __syncthreads();
  for (int s2 = 128; s2 > 0; s2 >>= 1) { if (t < s2) red[t] = fmaxf(red[t], red[t+s2]); __syncthreads(); }
  if (t == 0) atomicMax(scal+0, __float_as_uint(red[0]));
}

// ---------------- split a2 -> hi/lo planes; zc = a2^T/c -> hi/lo planes (LDS transpose)
__global__ __launch_bounds__(256) void k_split_init(
    const float* __restrict__ a2, const unsigned* __restrict__ scal,
    bf16u* __restrict__ a2h, bf16u* __restrict__ a2l,
    bf16u* __restrict__ zch, bf16u* __restrict__ zcl) {
  __shared__ bf16u Th[64][72], Tl[64][72];
  const int bh = blockIdx.y;
  const int tx = blockIdx.x & 3, ty = blockIdx.x >> 2;
  const int r0 = ty*64, c0 = tx*64;
  const size_t base = (size_t)bh<<16;
  const int t = threadIdx.x;
  const float rc = 1.0f/(__uint_as_float(scal[0]) * __uint_as_float(scal[1]));
  {
    int rr = t>>2, cc0 = (t&3)*16;
    const float* src = a2 + base + (size_t)(r0+rr)*256 + c0+cc0;
    bf16u hbuf[16], lbuf[16];
    #pragma unroll
    for (int u=0;u<4;++u) {
      float4 v = *(const float4*)(src + u*4);
      float vv[4] = {v.x,v.y,v.z,v.w};
      #pragma unroll
      for (int e=0;e<4;++e) {
        splt(vv[e], hbuf[u*4+e], lbuf[u*4+e]);
        bf16u zh_, zl_;
        splt(vv[e]*rc, zh_, zl_);
        Th[cc0+u*4+e][rr] = zh_;
        Tl[cc0+u*4+e][rr] = zl_;
      }
    }
    bf16u* dh = a2h + base + (size_t)(r0+rr)*256 + c0+cc0;
    bf16u* dl = a2l + base + (size_t)(r0+rr)*256 + c0+cc0;
    #pragma unroll
    for (int u=0;u<4;++u) {
      *(ushort4*)(dh + u*4) = *(ushort4*)&hbuf[u*4];
      *(ushort4*)(dl + u*4) = *(ushort4*)&lbuf[u*4];
    }
  }
  __syncthreads();
  {
    int cc = t>>2, rr0 = (t&3)*16;
    bf16u* dh = zch + base + (size_t)(c0+cc)*256 + r0+rr0;
    bf16u* dl = zcl + base + (size_t)(c0+cc)*256 + r0+rr0;
    #pragma unroll
    for (int u=0;u<4;++u) {
      *(ushort4*)(dh + u*4) = *(ushort4*)&Th[cc][rr0+u*4];
      *(ushort4*)(dl + u*4) = *(ushort4*)&Tl[cc][rr0+u*4];
    }
  }
}

// ---------------- NS pre-split pair GEMM (reg-staged, padded LDS; round-7 proven form)
template<int PHASE>
__global__ __launch_bounds__(256) void k_ns(
    const bf16u* __restrict__ Ah, const bf16u* __restrict__ Al,
    const bf16u* __restrict__ A2h, const bf16u* __restrict__ A2l,
    const bf16u* __restrict__ Bh_, const bf16u* __restrict__ Bl_,
    const bf16u* __restrict__ Xh, const bf16u* __restrict__ Xl,
    const bf16u* __restrict__ X2h, const bf16u* __restrict__ X2l,
    bf16u* __restrict__ Oh, bf16u* __restrict__ Ol,
    bf16u* __restrict__ O2h, bf16u* __restrict__ O2l,
    bf16u* __restrict__ Ch, bf16u* __restrict__ Cl,
    const unsigned* __restrict__ scal) {
  __shared__ short AhS[128][36], AlS[128][36], BhS[64][36], BlS[64][36];
  const int z = (gridDim.z == 2) ? blockIdx.z : (PHASE==2 ? 1 : 0);
  const int bh = blockIdx.y;
  const size_t base = (size_t)bh<<16;
  const int m0 = (blockIdx.x & 1)*128, n0 = (blockIdx.x >> 1)*64;
  const int t = threadIdx.x;
  const int wid = t>>6, l = t&63, lm = l&15, lg = l>>4;
  const int wr = (wid&1)*64, wc = (wid>>1)*32;
  const bf16u* pAh = z ? A2h : Ah;
  const bf16u* pAl = z ? A2l : Al;
  f32x4 acc[4][2];
  #pragma unroll
  for (int i=0;i<4;++i) { acc[i][0] = (f32x4){0,0,0,0}; acc[i][1] = (f32x4){0,0,0,0}; }
  for (int k0=0; k0<256; k0+=32) {
    #pragma unroll
    for (int i=0;i<2;++i) {
      int idx = t + i*256;
      int row = idx>>2, ch = (idx&3)<<3;
      *(uint4*)&AhS[row][ch] = *(const uint4*)(pAh + base + (size_t)(m0+row)*256 + k0+ch);
      *(uint4*)&AlS[row][ch] = *(const uint4*)(pAl + base + (size_t)(m0+row)*256 + k0+ch);
    }
    {
      int row = t>>2, ch = (t&3)<<3;
      *(uint4*)&BhS[row][ch] = *(const uint4*)(Bh_ + base + (size_t)(n0+row)*256 + k0+ch);
      *(uint4*)&BlS[row][ch] = *(const uint4*)(Bl_ + base + (size_t)(n0+row)*256 + k0+ch);
    }
    __syncthreads();
    short8 ah[4], al[4], sh[2], sl[2];
    #pragma unroll
    for (int mt=0;mt<4;++mt) {
      ah[mt] = *(const short8*)&AhS[wr+mt*16+lm][lg*8];
      al[mt] = *(const short8*)&AlS[wr+mt*16+lm][lg*8];
    }
    #pragma unroll
    for (int nt=0;nt<2;++nt) {
      sh[nt] = *(const short8*)&BhS[wc+nt*16+lm][lg*8];
      sl[nt] = *(const short8*)&BlS[wc+nt*16+lm][lg*8];
    }
    #pragma unroll
    for (int mt=0;mt<4;++mt)
      #pragma unroll
      for (int nt=0;nt<2;++nt) {
        acc[mt][nt] = MFMA16(ah[mt], sh[nt], acc[mt][nt]);
        acc[mt][nt] = MFMA16(ah[mt], sl[nt], acc[mt][nt]);
        acc[mt][nt] = MFMA16(al[mt], sh[nt], acc[mt][nt]);
      }
    __syncthreads();
  }
  float rc = 1.0f;
  if (PHASE==0) rc = 1.0f/(__uint_as_float(scal[0]) * __uint_as_float(scal[1]));
  #pragma unroll
  for (int mt=0;mt<4;++mt)
    #pragma unroll
    for (int nt=0;nt<2;++nt)
      #pragma unroll
      for (int r=0;r<4;++r) {
        int gr = m0 + wr + mt*16 + lg*4 + r;
        int gc = n0 + wc + nt*16 + lm;
        size_t idx = base + (size_t)gr*256 + gc;
        float a = acc[mt][nt][r];
        bf16u hh, ll;
        if (PHASE==0) {
          splt(a*rc, hh, ll); Oh[idx]=hh; Ol[idx]=ll;
        } else if (PHASE==1) {
          if (z==0) {
            splt(a, hh, ll); Oh[idx]=hh; Ol[idx]=ll;
            float wv = b2f(Xh[idx]) + b2f(Xl[idx]);
            float cb = ((gr==gc)?15.0f:0.0f) - 7.0f*wv + a;
            splt(cb, hh, ll); Ch[idx]=hh; Cl[idx]=ll;
          } else {
            splt(a, hh, ll); O2h[idx]=hh; O2l[idx]=ll;
          }
        } else {
          if (z==0) {
            float xv = b2f(Xh[idx]) + b2f(Xl[idx]);
            splt(3.25f*xv - 0.25f*a, hh, ll); Oh[idx]=hh; Ol[idx]=ll;
          } else {
            float xv = b2f(X2h[idx]) + b2f(X2l[idx]);
            splt(3.25f*xv - 0.25f*a, hh, ll); O2h[idx]=hh; O2l[idx]=ll;
          }
        }
      }
}

// ---------------- fused MFMA flash attention (no max-subtraction), reg-staged padded
template<int MODE>
__global__ __launch_bounds__(256) void k_flash(
    const bf16u* __restrict__ qg, const bf16u* __restrict__ kg,
    const bf16u* __restrict__ vtg, float* __restrict__ fpart, bf16u* __restrict__ outb) {
  constexpr int NCH = (MODE==0) ? (JS/64) : 4;
  const int bh = blockIdx.y;
  const int tile = blockIdx.x;
  const int t = threadIdx.x;
  const int wid = t>>6, l = t&63, lm = l&15, lg = l>>4;
  const size_t NQbase = (MODE==0) ? ((size_t)bh*NM) : ((size_t)bh*NSEQ + (size_t)tile*256);
  const int NJ = (MODE==0) ? NSEQ : NM;
  const int j0base = (MODE==0) ? tile*JS : 0;

  __shared__ short Ks[64][72];
  __shared__ short Vs[64][72];
  __shared__ short Pt[4][64][72];

  short8 qf[4][2];
  {
    const bf16u* qrow = qg + (NQbase + (size_t)wid*64) * DH;
    #pragma unroll
    for (int mt=0;mt<4;++mt)
      #pragma unroll
      for (int ks=0;ks<2;++ks)
        qf[mt][ks] = *(const short8*)(qrow + (size_t)(mt*16+lm)*DH + ks*32 + lg*8);
  }
  f32x4 oacc[4][4];
  #pragma unroll
  for (int i=0;i<4;++i)
    #pragma unroll
    for (int j=0;j<4;++j) oacc[i][j] = (f32x4){0,0,0,0};
  float rs[4][4];
  #pragma unroll
  for (int i=0;i<4;++i) { rs[i][0]=0; rs[i][1]=0; rs[i][2]=0; rs[i][3]=0; }

  const bf16u* kbh = kg  + (size_t)bh*NJ*DH;
  const bf16u* vbh = vtg + (size_t)bh*DH*NJ;

  for (int ch=0; ch<NCH; ++ch) {
    int j0 = j0base + ch*64;
    #pragma unroll
    for (int i=0;i<2;++i) {
      int c = t + i*256;
      int row = c>>3, kc = (c&7)<<3;
      *(uint4*)&Ks[row][kc] = *(const uint4*)(kbh + (size_t)(j0+row)*DH + kc);
      *(uint4*)&Vs[row][kc] = *(const uint4*)(vbh + (size_t)row*NJ + j0 + kc);
    }
    __syncthreads();
    short8 kf[4][2];
    #pragma unroll
    for (int jt=0;jt<4;++jt)
      #pragma unroll
      for (int ks=0;ks<2;++ks)
        kf[jt][ks] = *(const short8*)&Ks[jt*16+lm][ks*32+lg*8];
    #pragma unroll
    for (int mt=0;mt<4;++mt) {
      #pragma unroll
      for (int jt=0;jt<4;++jt) {
        f32x4 s = (f32x4){0,0,0,0};
        s = MFMA16(qf[mt][0], kf[jt][0], s);
        s = MFMA16(qf[mt][1], kf[jt][1], s);
        #pragma unroll
        for (int r=0;r<4;++r) {
          float p = __expf(s[r]);
          rs[mt][r] += p;
          Pt[wid][mt*16+lg*4+r][jt*16+lm] = f2b(p);
        }
      }
    }
    short8 vf[4][2];
    #pragma unroll
    for (int dt=0;dt<4;++dt)
      #pragma unroll
      for (int jw=0;jw<2;++jw)
        vf[dt][jw] = *(const short8*)&Vs[dt*16+lm][jw*32+lg*8];
    #pragma unroll
    for (int mt=0;mt<4;++mt) {
      short8 pa0 = *(const short8*)&Pt[wid][mt*16+lm][lg*8];
      short8 pa1 = *(const short8*)&Pt[wid][mt*16+lm][32+lg*8];
      #pragma unroll
      for (int dt=0;dt<4;++dt) {
        oacc[mt][dt] = MFMA16(pa0, vf[dt][0], oacc[mt][dt]);
        oacc[mt][dt] = MFMA16(pa1, vf[dt][1], oacc[mt][dt]);
      }
    }
    __syncthreads();
  }
  #pragma unroll
  for (int mt=0;mt<4;++mt)
    #pragma unroll
    for (int r=0;r<4;++r) {
      float v = rs[mt][r];
      v += __shfl_xor(v, 1); v += __shfl_xor(v, 2);
      v += __shfl_xor(v, 4); v += __shfl_xor(v, 8);
      rs[mt][r] = v;
    }
  if (MODE==0) {
    float* fb = fpart + (((size_t)bh*NSLICE + tile)*NM)*65;
    #pragma unroll
    for (int mt=0;mt<4;++mt)
      #pragma unroll
      for (int r=0;r<4;++r) {
        int row = wid*64 + mt*16 + lg*4 + r;
        float* fr = fb + (size_t)row*65;
        #pragma unroll
        for (int dt=0;dt<4;++dt) fr[dt*16+lm] = oacc[mt][dt][r];
        if (lm==0) fr[64] = rs[mt][r];
      }
  } else {
    const int b_ = bh>>3, h_ = bh&7;
    #pragma unroll
    for (int mt=0;mt<4;++mt)
      #pragma unroll
      for (int r=0;r<4;++r) {
        float inv = 1.0f/rs[mt][r];
        int n = tile*256 + wid*64 + mt*16 + lg*4 + r;
        bf16u* orow = outb + ((size_t)b_*NSEQ + n)*DIMC + h_*DH;
        #pragma unroll
        for (int dt=0;dt<4;++dt)
          orow[dt*16+lm] = f2b(oacc[mt][dt][r]*inv);
      }
  }
}

// combine -> w1T fp32 [bh][64][256]
__global__ __launch_bounds__(256) void k_attn3v_combine(
    const float* __restrict__ fpart, float* __restrict__ w1T) {
  int gi = blockIdx.x*4 + (threadIdx.x>>6);
  int d = threadIdx.x & 63;
  int bh = gi >> 8, i = gi & 255;
  float accd = 0, ssum = 0;
  #pragma unroll
  for (int s = 0; s < NSLICE; ++s) {
    const float* fp = fpart + (((size_t)bh*NSLICE + s)*NM + i)*65;
    accd += fp[d];
    ssum += fp[64];
  }
  w1T[((size_t)bh*64 + d)*256 + i] = accd / ssum;
}

// ---------------- w2T[bh][64][256] = w1T @ z^T  (z planes pre-split; A split in-loader)
__global__ __launch_bounds__(256) void k_w2nat(
    const float* __restrict__ w1T, const bf16u* __restrict__ zh, const bf16u* __restrict__ zl,
    bf16u* __restrict__ w2T) {
  __shared__ short Ah[64][36], Al[64][36], Bh[64][36], Bl[64][36];
  const int bh = blockIdx.y;
  const int n0 = blockIdx.x*64;
  const size_t a0 = (size_t)bh*64*256;
  const size_t s0 = (size_t)bh<<16;
  const int t = threadIdx.x;
  const int wid = t>>6, l = t&63, lm = l&15, lg = l>>4;
  const int wc = wid*16;
  f32x4 acc[4];
  #pragma unroll
  for (int i=0;i<4;++i) acc[i] = (f32x4){0,0,0,0};
  for (int k0=0; k0<256; k0+=32) {
    #pragma unroll
    for (int i=0;i<2;++i) {
      int idx = t + i*256;
      int row = idx>>3, kc = (idx&7)<<2;
      float4 v = *(const float4*)(w1T + a0 + (size_t)row*256 + k0+kc);
      ushort4 hh, ll;
      splt(v.x, hh.x, ll.x); splt(v.y, hh.y, ll.y);
      splt(v.z, hh.z, ll.z); splt(v.w, hh.w, ll.w);
      *(ushort4*)&Ah[row][kc] = hh; *(ushort4*)&Al[row][kc] = ll;
    }
    {
      int row = t>>2, ch = (t&3)<<3;
      *(uint4*)&Bh[row][ch] = *(const uint4*)(zh + s0 + (size_t)(n0+row)*256 + k0+ch);
      *(uint4*)&Bl[row][ch] = *(const uint4*)(zl + s0 + (size_t)(n0+row)*256 + k0+ch);
    }
    __syncthreads();
    short8 sh = *(const short8*)&Bh[wc+lm][lg*8];
    short8 sl = *(const short8*)&Bl[wc+lm][lg*8];
    #pragma unroll
    for (int mt=0;mt<4;++mt) {
      short8 ah = *(const short8*)&Ah[mt*16+lm][lg*8];
      short8 al = *(const short8*)&Al[mt*16+lm][lg*8];
      acc[mt] = MFMA16(ah, sh, acc[mt]);
      acc[mt] = MFMA16(ah, sl, acc[mt]);
      acc[mt] = MFMA16(al, sh, acc[mt]);
    }
    __syncthreads();
  }
  #pragma unroll
  for (int mt=0;mt<4;++mt)
    #pragma unroll
    for (int r=0;r<4;++r) {
      int gm = mt*16 + lg*4 + r;
      w2T[a0 + (size_t)gm*256 + n0 + wc + lm] = f2b(acc[mt][r]);
    }
}

// ---------------- depthwise conv residual from vT, LDS-transposed staging
__global__ __launch_bounds__(256) void k_conv_add(
    const bf16u* __restrict__ vt, const float* __restrict__ wc, bf16u* __restrict__ outb) {
  __shared__ short Vs[288][72];
  __shared__ float Wsh[40];
  const int bh = blockIdx.y, n0 = blockIdx.x*256;
  const int b_ = bh>>3, h_ = bh&7;
  const int t = threadIdx.x;
  if (t < KW) Wsh[t] = wc[h_*KW + t];
  const bf16u* vrow = vt + (size_t)bh*DH*NSEQ;
  {
    int d = t&63, seg = t>>6;
    #pragma unroll
    for (int u=0; u<9; ++u) {
      int nl = seg*72 + u*8;
      int gn = n0 - 16 + nl;
      bf16u e8[8];
      if (gn >= 0 && gn + 8 <= NSEQ) {
        *(uint4*)e8 = *(const uint4*)(vrow + (size_t)d*NSEQ + gn);
      } else {
        #pragma unroll
        for (int e=0;e<8;++e) {
          int g = gn + e;
          e8[e] = (g>=0 && g<NSEQ) ? vrow[(size_t)d*NSEQ + g] : (bf16u)0;
        }
      }
      #pragma unroll
      for (int e=0;e<8;++e) Vs[nl+e][d] = e8[e];
    }
  }
  __syncthreads();
  const int d = t&63, q = t>>6;
  #pragma unroll
  for (int c2=0;c2<4;++c2) {
    int nb = q*64 + c2*16;
    float wv[48];
    #pragma unroll
    for (int i=0;i<48;++i) wv[i] = b2f(Vs[nb+i][d]);
    #pragma unroll
    for (int e=0;e<16;++e) {
      float s = 0;
      #pragma unroll
      for (int k=0;k<KW;++k) s = fmaf(wv[e+k], Wsh[k], s);
      size_t oi = ((size_t)b_*NSEQ + n0 + nb + e)*DIMC + h_*DH + d;
      outb[oi] = f2b(b2f(outb[oi]) + s);
    }
  }
}

extern "C" void kernel_launch(void* const* d_in, const int* in_sizes, int n_in,
                              void* d_out, int out_size, void* d_ws, size_t ws_size,
                              hipStream_t stream) {
  (void)in_sizes; (void)n_in;
  const float* x      = (const float*)d_in[0];
  const float* w_qkv  = (const float*)d_in[1];
  const float* w_out  = (const float*)d_in[2];
  const float* b_out  = (const float*)d_in[3];
  const float* w_conv = (const float*)d_in[4];
  float* out = (float*)d_out;

  const size_t QKV_E = (size_t)BHN*NSEQ*DH;   // 16,777,216
  const size_t LM_E  = (size_t)BHN*NM*DH;     // 524,288
  const size_t MM_E  = (size_t)BHN*NM*NM;     // 2,097,152
  const size_t PLSZ  = MM_E*2;                // one bf16 plane = 4 MiB

  char* p = (char*)d_ws;
  char* nsb   = p;          p += 9*PLSZ;      // 36 MiB: NS planes P0..P7 + spare (fpart 34.1)
  bf16u* zch  = (bf16u*)p;  p += PLSZ;
  bf16u* zcl  = (bf16u*)p;  p += PLSZ;
  bf16u* qb    = (bf16u*)p; p += QKV_E*2;
  bf16u* kb    = (bf16u*)p; p += QKV_E*2;     // (-> outb)
  bf16u* vT    = (bf16u*)p; p += QKV_E*2;
  bf16u* wqkvT = (bf16u*)p; p += (size_t)DIMC*3*DIMC*2;
  bf16u* woutT = (bf16u*)p; p += (size_t)DIMC*DIMC*2;
  float* ql    = (float*)p; p += LM_E*4;
  float* klm   = (float*)p; p += LM_E*4;
  bf16u* qlb   = (bf16u*)p; p += LM_E*2;
  bf16u* klmb  = (bf16u*)p; p += LM_E*2;
  float* w1T   = (float*)p; p += LM_E*4;
  bf16u* w2T   = (bf16u*)p; p += LM_E*2;
  unsigned* scal = (unsigned*)p; p += 256;
  size_t need = (size_t)(p - (char*)d_ws);

  if (ws_size < need) {
    k_fill<<<(out_size + 255)/256, 256, 0, stream>>>(out, out_size, 12345.0f);
    return;
  }

  bf16u* a2h  = (bf16u*)(nsb + 0*PLSZ);
  bf16u* a2l  = (bf16u*)(nsb + 1*PLSZ);
  bf16u* s1h  = (bf16u*)(nsb + 2*PLSZ);
  bf16u* s1l  = (bf16u*)(nsb + 3*PLSZ);
  bf16u* cmh  = (bf16u*)(nsb + 4*PLSZ);
  bf16u* cml  = (bf16u*)(nsb + 5*PLSZ);
  bf16u* wh   = (bf16u*)(nsb + 6*PLSZ);
  bf16u* wl   = (bf16u*)(nsb + 7*PLSZ);
  float* a2f  = (float*)(nsb + 2*PLSZ);
  float* fpart = (float*)nsb;
  bf16u* c1h = a2h; bf16u* c1l = a2l;
  bf16u* xb  = (bf16u*)nsb;

  // 1. converts
  c_prep<<<12288, 256, 0, stream>>>(x, w_qkv, w_out, xb, wqkvT, woutT);
  // 2. qkv projection (MFMA, XCD-chunked swizzle)
  k_mgemm<0><<<3072, 256, 0, stream>>>(xb, wqkvT, DIMC, 12, qb, kb, vT, nullptr, nullptr);
  // 3. landmarks
  k_landmarks<<<(BHN*NM)/4, 256, 0, stream>>>(qb, kb, ql, klm, qlb, klmb);
  // 4. attn2 = softmax(ql@klm^T)
  k_qlk_exp<<<dim3(8, BHN), 256, 0, stream>>>(ql, klm, a2f, DH);
  k_rowsm<<<BHN*NM/4, 256, 0, stream>>>(a2f, scal);
  // 5. pinv init
  k_pinv_reduce<<<BHN, 256, 0, stream>>>(a2f, scal);
  k_split_init<<<dim3(16, BHN), 256, 0, stream>>>(a2f, scal, a2h, a2l, zch, zcl);
  k_ns<0><<<dim3(8, BHN, 1), 256, 0, stream>>>(
      a2h,a2l, nullptr,nullptr, a2h,a2l, nullptr,nullptr, nullptr,nullptr,
      wh,wl, nullptr,nullptr, nullptr,nullptr, scal);
  // 6. Newton-Schulz, 2 launches/iter, in-place w,z
  for (int it = 0; it < NITER; ++it) {
    k_ns<1><<<dim3(8, BHN, 2), 256, 0, stream>>>(
        wh,wl, zch,zcl, wh,wl, wh,wl, nullptr,nullptr,
        s1h,s1l, c1h,c1l, cmh,cml, nullptr);
    k_ns<2><<<dim3(8, BHN, (it==NITER-1)?1:2), 256, 0, stream>>>(
        s1h,s1l, c1h,c1l, cmh,cml, wh,wl, zch,zcl,
        wh,wl, zch,zcl, nullptr,nullptr, nullptr);
  }
  // 7. w1 = softmax(ql@k^T)@v (MFMA flash, 16 slices) -> w1T
  k_flash<0><<<dim3(NSLICE, BHN), 256, 0, stream>>>(qlb, kb, vT, fpart, nullptr);
  k_attn3v_combine<<<(BHN*NM)/4, 256, 0, stream>>>(fpart, w1T);
  // 8. w2T = w1T @ z^T
  k_w2nat<<<dim3(4, BHN), 256, 0, stream>>>(w1T, zch, zcl, w2T);
  // 9. attn1 @ w2 -> outb (MFMA flash)
  bf16u* outb = kb;
  k_flash<1><<<dim3(NSEQ/256, BHN), 256, 0, stream>>>(qb, klmb, w2T, nullptr, outb);
  // 10. conv residual
  k_conv_add<<<dim3(NSEQ/256, BHN), 256, 0, stream>>>(vT, w_conv, outb);
  // 11. output projection
  k_mgemm<1><<<1024, 256, 0, stream>>>(outb, woutT, DIMC, 4, nullptr, nullptr, nullptr, b_out, out);
}

// Round 12
// 583.187 us; speedup vs baseline: 8.3901x; 1.1934x over previous
//
#include <hip/hip_runtime.h>
#include <cstdint>
#include <cstddef>

#define BQ 4
#define NSEQ 8192
#define DIMC 512
#define NH 8
#define DH 64
#define NM 256
#define NITER 6
#define KW 33
#define BHN (BQ*NH)
#define NSLICE 16
#define JS (NSEQ/NSLICE)

typedef unsigned short bf16u;
typedef __attribute__((ext_vector_type(8))) short short8;
typedef __attribute__((ext_vector_type(4))) float f32x4;
#define MFMA16(a,b,c) __builtin_amdgcn_mfma_f32_16x16x32_bf16(a,b,c,0,0,0)

__device__ inline float b2f(bf16u u) { return __uint_as_float(((unsigned int)u) << 16); }
__device__ inline bf16u f2b(float f) {
  unsigned int u = __float_as_uint(f);
  unsigned int r = (u + 0x7fffu + ((u >> 16) & 1u)) >> 16;  // RNE
  return (bf16u)r;
}
// truncation split: v = hi + lo + O(2^-17 |v|)
__device__ inline void splt(float v, unsigned short& h, unsigned short& l) {
  unsigned u = __float_as_uint(v);
  h = (unsigned short)(u >> 16);
  float hf = __uint_as_float(u & 0xffff0000u);
  l = (unsigned short)(__float_as_uint(v - hf) >> 16);
}

__global__ __launch_bounds__(256) void k_fill(float* out, int n, float v) {
  int i = blockIdx.x * 256 + threadIdx.x;
  if (i < n) out[i] = v;
}

// ---------------- merged prep: x->bf16, w_qkv^T->bf16, w_out^T->bf16
__global__ __launch_bounds__(256) void c_prep(
    const float* __restrict__ x, const float* __restrict__ w_qkv, const float* __restrict__ w_out,
    bf16u* __restrict__ xb, bf16u* __restrict__ wqkvT, bf16u* __restrict__ woutT) {
  int id = blockIdx.x;
  if (id < 8192) {
    int i = id*256 + threadIdx.x;
    const float4* s = (const float4*)(x + (size_t)i*8);
    float4 a = s[0], b = s[1];
    ushort4 lo, hi;
    lo.x=f2b(a.x); lo.y=f2b(a.y); lo.z=f2b(a.z); lo.w=f2b(a.w);
    hi.x=f2b(b.x); hi.y=f2b(b.y); hi.z=f2b(b.z); hi.w=f2b(b.w);
    ushort4* d = (ushort4*)(xb + (size_t)i*8);
    d[0] = lo; d[1] = hi;
  } else if (id < 8192+3072) {
    int i = (id-8192)*256 + threadIdx.x;
    int r = i / 1536, c = i - r*1536;
    wqkvT[(size_t)c*DIMC + r] = f2b(w_qkv[i]);
  } else {
    int i = (id-11264)*256 + threadIdx.x;
    int r = i >> 9, c = i & 511;
    woutT[(size_t)c*DIMC + r] = f2b(w_out[i]);
  }
}

// ---------------- MFMA GEMM  C[M,-] = A[M,K](bf16) @ Bt[N,K]^T(bf16)
// reg-staged, padded LDS [72]; XCD-chunked block swizzle. (round-7 proven form)
template<int MODE>
__global__ __launch_bounds__(256) void k_mgemm(
    const bf16u* __restrict__ A, const bf16u* __restrict__ Bt, int K, int nb,
    bf16u* __restrict__ oq, bf16u* __restrict__ ok, bf16u* __restrict__ ovT,
    const float* __restrict__ bias, float* __restrict__ oC) {
  __shared__ short As[128][72];
  __shared__ short Bs[128][72];
  const int id = blockIdx.x;
  const int rid = (id & 7) * ((int)gridDim.x >> 3) + (id >> 3);
  const int m0 = (rid / nb) * 128, n0 = (rid % nb) * 128;
  const int t = threadIdx.x;
  const int wid = t>>6, l = t&63, lm = l&15, lg = l>>4;
  const int wr = (wid>>1)*64, wc = (wid&1)*64;
  f32x4 acc[4][4];
  #pragma unroll
  for (int i=0;i<4;++i)
    #pragma unroll
    for (int j=0;j<4;++j) acc[i][j] = (f32x4){0,0,0,0};
  for (int k0=0; k0<K; k0+=64) {
    #pragma unroll
    for (int i=0;i<4;++i) {
      int c = t + i*256;
      int row = c>>3, kc = (c&7)<<3;
      *(uint4*)&As[row][kc] = *(const uint4*)(A  + (size_t)(m0+row)*K + k0+kc);
      *(uint4*)&Bs[row][kc] = *(const uint4*)(Bt + (size_t)(n0+row)*K + k0+kc);
    }
    __syncthreads();
    #pragma unroll
    for (int ks=0;ks<2;++ks) {
      short8 af[4], bfr[4];
      #pragma unroll
      for (int i=0;i<4;++i) {
        af[i]  = *(const short8*)&As[wr+i*16+lm][ks*32+lg*8];
        bfr[i] = *(const short8*)&Bs[wc+i*16+lm][ks*32+lg*8];
      }
      #pragma unroll
      for (int i=0;i<4;++i)
        #pragma unroll
        for (int j=0;j<4;++j)
          acc[i][j] = MFMA16(af[i], bfr[j], acc[i][j]);
    }
    __syncthreads();
  }
  if (MODE==0) {
    #pragma unroll
    for (int mt=0;mt<4;++mt) {
      int grb = m0 + wr + mt*16 + lg*4;
      int b_ = grb>>13, nrow = grb & (NSEQ-1);
      #pragma unroll
      for (int nt=0;nt<4;++nt) {
        int gc = n0 + wc + nt*16 + lm;
        int which = gc>>9, h_ = (gc>>6)&7, d = gc&63;
        if (which==2) {
          ushort4 pk;
          pk.x=f2b(acc[mt][nt][0]); pk.y=f2b(acc[mt][nt][1]);
          pk.z=f2b(acc[mt][nt][2]); pk.w=f2b(acc[mt][nt][3]);
          *(ushort4*)(ovT + (((size_t)b_*NH+h_)*DH + d)*NSEQ + nrow) = pk;
        } else {
          bf16u* dst = (which==0) ? oq : ok;
          float mul = (which==0) ? 0.125f : 1.0f;
          #pragma unroll
          for (int r=0;r<4;++r)
            dst[(((size_t)b_*NH+h_)*NSEQ + nrow + r)*DH + d] = f2b(acc[mt][nt][r]*mul);
        }
      }
    }
  } else {
    #pragma unroll
    for (int mt=0;mt<4;++mt)
      #pragma unroll
      for (int r=0;r<4;++r) {
        int gr = m0 + wr + mt*16 + lg*4 + r;
        #pragma unroll
        for (int nt=0;nt<4;++nt) {
          int gc = n0 + wc + nt*16 + lm;
          oC[(size_t)gr*DIMC + gc] = acc[mt][nt][r] + bias[gc];
        }
      }
  }
}

// ---------------- landmark means over blocks of 32
__global__ __launch_bounds__(256) void k_landmarks(
    const bf16u* __restrict__ q, const bf16u* __restrict__ kbuf,
    float* __restrict__ ql, float* __restrict__ klm,
    bf16u* __restrict__ qlb, bf16u* __restrict__ klmb) {
  int gi = blockIdx.x*4 + (threadIdx.x>>6);
  int d = threadIdx.x & 63;
  int bh = gi >> 8, i = gi & 255;
  size_t srcoff = ((size_t)bh*NSEQ + (size_t)i*32)*DH + d;
  float sq = 0, sk = 0;
  #pragma unroll
  for (int j = 0; j < 32; ++j) {
    sq += b2f(q[srcoff + (size_t)j*DH]);
    sk += b2f(kbuf[srcoff + (size_t)j*DH]);
  }
  float mq = sq * (1.0f/32.0f), mk = sk * (1.0f/32.0f);
  ql[(size_t)gi*DH + d]  = mq;  klm[(size_t)gi*DH + d]  = mk;
  qlb[(size_t)gi*DH + d] = f2b(mq); klmb[(size_t)gi*DH + d] = f2b(mk);
}

// ---------------- split-bf16 MFMA GEMM for attn2: C = exp(A @ S^T), in-loader split
__global__ __launch_bounds__(256) void k_qlk_exp(
    const float* __restrict__ A, const float* __restrict__ S, float* __restrict__ C, int K) {
  __shared__ short Ah[128][40], Al[128][40], Bh[64][40], Bl[64][40];
  const int bh = blockIdx.y;
  const size_t abase = (size_t)bh*256*K;
  const size_t cbase = (size_t)bh<<16;
  const int m0 = (blockIdx.x & 1)*128, n0 = (blockIdx.x >> 1)*64;
  const int t = threadIdx.x;
  const int wid = t>>6, l = t&63, lm = l&15, lg = l>>4;
  const int wr = (wid&1)*64, wc = (wid>>1)*32;
  f32x4 acc[4][2];
  #pragma unroll
  for (int i=0;i<4;++i) { acc[i][0] = (f32x4){0,0,0,0}; acc[i][1] = (f32x4){0,0,0,0}; }
  for (int k0=0; k0<K; k0+=32) {
    #pragma unroll
    for (int i=0;i<4;++i) {
      int idx = t + i*256;
      int row = idx>>3, kc = (idx&7)<<2;
      float4 v = *(const float4*)(A + abase + (size_t)(m0+row)*K + k0+kc);
      ushort4 hh, ll;
      splt(v.x, hh.x, ll.x); splt(v.y, hh.y, ll.y);
      splt(v.z, hh.z, ll.z); splt(v.w, hh.w, ll.w);
      *(ushort4*)&Ah[row][kc] = hh; *(ushort4*)&Al[row][kc] = ll;
    }
    #pragma unroll
    for (int i=0;i<2;++i) {
      int idx = t + i*256;
      int row = idx>>3, kc = (idx&7)<<2;
      float4 v = *(const float4*)(S + abase + (size_t)(n0+row)*K + k0+kc);
      ushort4 hh, ll;
      splt(v.x, hh.x, ll.x); splt(v.y, hh.y, ll.y);
      splt(v.z, hh.z, ll.z); splt(v.w, hh.w, ll.w);
      *(ushort4*)&Bh[row][kc] = hh; *(ushort4*)&Bl[row][kc] = ll;
    }
    __syncthreads();
    short8 ah[4], al[4], sh[2], sl[2];
    #pragma unroll
    for (int mt=0;mt<4;++mt) {
      ah[mt] = *(const short8*)&Ah[wr+mt*16+lm][lg*8];
      al[mt] = *(const short8*)&Al[wr+mt*16+lm][lg*8];
    }
    #pragma unroll
    for (int nt=0;nt<2;++nt) {
      sh[nt] = *(const short8*)&Bh[wc+nt*16+lm][lg*8];
      sl[nt] = *(const short8*)&Bl[wc+nt*16+lm][lg*8];
    }
    #pragma unroll
    for (int mt=0;mt<4;++mt)
      #pragma unroll
      for (int nt=0;nt<2;++nt) {
        acc[mt][nt] = MFMA16(ah[mt], sh[nt], acc[mt][nt]);
        acc[mt][nt] = MFMA16(ah[mt], sl[nt], acc[mt][nt]);
        acc[mt][nt] = MFMA16(al[mt], sh[nt], acc[mt][nt]);
      }
    __syncthreads();
  }
  #pragma unroll
  for (int mt=0;mt<4;++mt)
    #pragma unroll
    for (int nt=0;nt<2;++nt)
      #pragma unroll
      for (int r=0;r<4;++r) {
        int gr = m0 + wr + mt*16 + lg*4 + r;
        int gc = n0 + wc + nt*16 + lm;
        C[cbase + (size_t)gr*256 + gc] = __expf(acc[mt][nt][r]);
      }
}

// ---------------- row softmax-normalize (+ zero scal, block 0)
__global__ __launch_bounds__(256) void k_rowsm(float* __restrict__ a2, unsigned* __restrict__ scal) {
  if (blockIdx.x == 0 && threadIdx.x < 2) scal[threadIdx.x] = 0u;
  int row = blockIdx.x*4 + (threadIdx.x>>6);
  int l = threadIdx.x & 63;
  float4* p = (float4*)(a2 + (size_t)row*256 + l*4);
  float4 v = *p;
  float s = v.x+v.y+v.z+v.w;
  #pragma unroll
  for (int d=1; d<64; d<<=1) s += __shfl_xor(s, d);
  float inv = 1.0f/s;
  v.x*=inv; v.y*=inv; v.z*=inv; v.w*=inv;
  *p = v;
}

// ---------------- pinv init reductions (coalesced; one block per bh)
__global__ __launch_bounds__(256) void k_pinv_reduce(const float* __restrict__ a2, unsigned* scal) {
  const int bh = blockIdx.x, t = threadIdx.x;
  const int wv = t>>6, lane = t&63;
  const float* A = a2 + (size_t)bh*NM*NM;
  float cs = 0;
  for (int r = 0; r < NM; ++r) cs += fabsf(A[(size_t)r*NM + t]);
  float rmax = 0;
  for (int i = 0; i < 64; ++i) {
    int r = wv*64 + i;
    float4 v = *(const float4*)(A + (size_t)r*NM + lane*4);
    float s = fabsf(v.x)+fabsf(v.y)+fabsf(v.z)+fabsf(v.w);
    #pragma unroll
    for (int d=1; d<64; d<<=1) s += __shfl_xor(s, d);
    rmax = fmaxf(rmax, s);
  }
  __shared__ float red[256];
  red[t] = cs; __syncthreads();
  for (int s2 = 128; s2 > 0; s2 >>= 1) { if (t < s2) red[t] = fmaxf(red[t], red[t+s2]); __syncthreads(); }
  if (t == 0) atomicMax(scal+1, __float_as_uint(red[0]));
  __syncthreads();
  red[t] = rmax; __syncthreads();
  for (int s2 = 128; s2 > 0; s2 >>= 1) { if (t < s2) red[t] = fmaxf(red[t], red[t+s2]); __syncthreads(); }
  if (t == 0) atomicMax(scal+0, __float_as_uint(red[0]));
}

// ---------------- a2 -> bf16 plane; zc = a2^T/c -> bf16 plane (LDS transpose)
__global__ __launch_bounds__(256) void k_init_b(
    const float* __restrict__ a2, const unsigned* __restrict__ scal,
    bf16u* __restrict__ a2b, bf16u* __restrict__ zcb) {
  __shared__ bf16u Th[64][72];
  const int bh = blockIdx.y;
  const int tx = blockIdx.x & 3, ty = blockIdx.x >> 2;
  const int r0 = ty*64, c0 = tx*64;
  const size_t base = (size_t)bh<<16;
  const int t = threadIdx.x;
  const float rc = 1.0f/(__uint_as_float(scal[0]) * __uint_as_float(scal[1]));
  {
    int rr = t>>2, cc0 = (t&3)*16;
    const float* src = a2 + base + (size_t)(r0+rr)*256 + c0+cc0;
    bf16u hbuf[16];
    #pragma unroll
    for (int u=0;u<4;++u) {
      float4 v = *(const float4*)(src + u*4);
      float vv[4] = {v.x,v.y,v.z,v.w};
      #pragma unroll
      for (int e=0;e<4;++e) {
        hbuf[u*4+e] = f2b(vv[e]);
        Th[cc0+u*4+e][rr] = f2b(vv[e]*rc);
      }
    }
    bf16u* dh = a2b + base + (size_t)(r0+rr)*256 + c0+cc0;
    #pragma unroll
    for (int u=0;u<4;++u) *(ushort4*)(dh + u*4) = *(ushort4*)&hbuf[u*4];
  }
  __syncthreads();
  {
    int cc = t>>2, rr0 = (t&3)*16;
    bf16u* dh = zcb + base + (size_t)(c0+cc)*256 + r0+rr0;
    #pragma unroll
    for (int u=0;u<4;++u) *(ushort4*)(dh + u*4) = *(ushort4*)&Th[cc][rr0+u*4];
  }
}

// ---------------- NS bf16 pair GEMM (single-plane, 1 MFMA/product)
// PHASE 0: O = acc*rc.  PHASE 1: z0: O=s1=acc, C_=15I-7X+acc; z1: O2=acc.
// PHASE 2: z0: O = 3.25X - 0.25acc; z1: O2 = 3.25X2 - 0.25acc.
template<int PHASE>
__global__ __launch_bounds__(256) void k_ns(
    const bf16u* __restrict__ A, const bf16u* __restrict__ A2,
    const bf16u* __restrict__ B_,
    const bf16u* __restrict__ X, const bf16u* __restrict__ X2,
    bf16u* __restrict__ O, bf16u* __restrict__ O2, bf16u* __restrict__ C_,
    const unsigned* __restrict__ scal) {
  __shared__ short AS[128][36], BS[64][36];
  const int z = (gridDim.z == 2) ? blockIdx.z : (PHASE==2 ? 1 : 0);
  const int bh = blockIdx.y;
  const size_t base = (size_t)bh<<16;
  const int m0 = (blockIdx.x & 1)*128, n0 = (blockIdx.x >> 1)*64;
  const int t = threadIdx.x;
  const int wid = t>>6, l = t&63, lm = l&15, lg = l>>4;
  const int wr = (wid&1)*64, wc = (wid>>1)*32;
  const bf16u* pA = z ? A2 : A;
  f32x4 acc[4][2];
  #pragma unroll
  for (int i=0;i<4;++i) { acc[i][0] = (f32x4){0,0,0,0}; acc[i][1] = (f32x4){0,0,0,0}; }
  for (int k0=0; k0<256; k0+=32) {
    #pragma unroll
    for (int i=0;i<2;++i) {
      int idx = t + i*256;
      int row = idx>>2, ch = (idx&3)<<3;
      *(uint4*)&AS[row][ch] = *(const uint4*)(pA + base + (size_t)(m0+row)*256 + k0+ch);
    }
    {
      int row = t>>2, ch = (t&3)<<3;
      if (t < 256) *(uint4*)&BS[row & 63][ch] = *(const uint4*)(B_ + base + (size_t)(n0+(row&63))*256 + k0+ch);
    }
    __syncthreads();
    short8 ah[4], sb[2];
    #pragma unroll
    for (int mt=0;mt<4;++mt) ah[mt] = *(const short8*)&AS[wr+mt*16+lm][lg*8];
    #pragma unroll
    for (int nt=0;nt<2;++nt) sb[nt] = *(const short8*)&BS[wc+nt*16+lm][lg*8];
    #pragma unroll
    for (int mt=0;mt<4;++mt)
      #pragma unroll
      for (int nt=0;nt<2;++nt)
        acc[mt][nt] = MFMA16(ah[mt], sb[nt], acc[mt][nt]);
    __syncthreads();
  }
  float rc = 1.0f;
  if (PHASE==0) rc = 1.0f/(__uint_as_float(scal[0]) * __uint_as_float(scal[1]));
  #pragma unroll
  for (int mt=0;mt<4;++mt)
    #pragma unroll
    for (int nt=0;nt<2;++nt)
      #pragma unroll
      for (int r=0;r<4;++r) {
        int gr = m0 + wr + mt*16 + lg*4 + r;
        int gc = n0 + wc + nt*16 + lm;
        size_t idx = base + (size_t)gr*256 + gc;
        float a = acc[mt][nt][r];
        if (PHASE==0) {
          O[idx] = f2b(a*rc);
        } else if (PHASE==1) {
          if (z==0) {
            O[idx] = f2b(a);
            float wv = b2f(X[idx]);
            C_[idx] = f2b(((gr==gc)?15.0f:0.0f) - 7.0f*wv + a);
          } else {
            O2[idx] = f2b(a);
          }
        } else {
          if (z==0) O[idx]  = f2b(3.25f*b2f(X[idx])  - 0.25f*a);
          else      O2[idx] = f2b(3.25f*b2f(X2[idx]) - 0.25f*a);
        }
      }
}

// ---------------- fused MFMA flash attention (no max-subtraction), reg-staged padded
template<int MODE>
__global__ __launch_bounds__(256) void k_flash(
    const bf16u* __restrict__ qg, const bf16u* __restrict__ kg,
    const bf16u* __restrict__ vtg, float* __restrict__ fpart, bf16u* __restrict__ outb) {
  constexpr int NCH = (MODE==0) ? (JS/64) : 4;
  const int bh = blockIdx.y;
  const int tile = blockIdx.x;
  const int t = threadIdx.x;
  const int wid = t>>6, l = t&63, lm = l&15, lg = l>>4;
  const size_t NQbase = (MODE==0) ? ((size_t)bh*NM) : ((size_t)bh*NSEQ + (size_t)tile*256);
  const int NJ = (MODE==0) ? NSEQ : NM;
  const int j0base = (MODE==0) ? tile*JS : 0;

  __shared__ short Ks[64][72];
  __shared__ short Vs[64][72];
  __shared__ short Pt[4][64][72];

  short8 qf[4][2];
  {
    const bf16u* qrow = qg + (NQbase + (size_t)wid*64) * DH;
    #pragma unroll
    for (int mt=0;mt<4;++mt)
      #pragma unroll
      for (int ks=0;ks<2;++ks)
        qf[mt][ks] = *(const short8*)(qrow + (size_t)(mt*16+lm)*DH + ks*32 + lg*8);
  }
  f32x4 oacc[4][4];
  #pragma unroll
  for (int i=0;i<4;++i)
    #pragma unroll
    for (int j=0;j<4;++j) oacc[i][j] = (f32x4){0,0,0,0};
  float rs[4][4];
  #pragma unroll
  for (int i=0;i<4;++i) { rs[i][0]=0; rs[i][1]=0; rs[i][2]=0; rs[i][3]=0; }

  const bf16u* kbh = kg  + (size_t)bh*NJ*DH;
  const bf16u* vbh = vtg + (size_t)bh*DH*NJ;

  for (int ch=0; ch<NCH; ++ch) {
    int j0 = j0base + ch*64;
    #pragma unroll
    for (int i=0;i<2;++i) {
      int c = t + i*256;
      int row = c>>3, kc = (c&7)<<3;
      *(uint4*)&Ks[row][kc] = *(const uint4*)(kbh + (size_t)(j0+row)*DH + kc);
      *(uint4*)&Vs[row][kc] = *(const uint4*)(vbh + (size_t)row*NJ + j0 + kc);
    }
    __syncthreads();
    short8 kf[4][2];
    #pragma unroll
    for (int jt=0;jt<4;++jt)
      #pragma unroll
      for (int ks=0;ks<2;++ks)
        kf[jt][ks] = *(const short8*)&Ks[jt*16+lm][ks*32+lg*8];
    #pragma unroll
    for (int mt=0;mt<4;++mt) {
      #pragma unroll
      for (int jt=0;jt<4;++jt) {
        f32x4 s = (f32x4){0,0,0,0};
        s = MFMA16(qf[mt][0], kf[jt][0], s);
        s = MFMA16(qf[mt][1], kf[jt][1], s);
        #pragma unroll
        for (int r=0;r<4;++r) {
          float p = __expf(s[r]);
          rs[mt][r] += p;
          Pt[wid][mt*16+lg*4+r][jt*16+lm] = f2b(p);
        }
      }
    }
    short8 vf[4][2];
    #pragma unroll
    for (int dt=0;dt<4;++dt)
      #pragma unroll
      for (int jw=0;jw<2;++jw)
        vf[dt][jw] = *(const short8*)&Vs[dt*16+lm][jw*32+lg*8];
    #pragma unroll
    for (int mt=0;mt<4;++mt) {
      short8 pa0 = *(const short8*)&Pt[wid][mt*16+lm][lg*8];
      short8 pa1 = *(const short8*)&Pt[wid][mt*16+lm][32+lg*8];
      #pragma unroll
      for (int dt=0;dt<4;++dt) {
        oacc[mt][dt] = MFMA16(pa0, vf[dt][0], oacc[mt][dt]);
        oacc[mt][dt] = MFMA16(pa1, vf[dt][1], oacc[mt][dt]);
      }
    }
    __syncthreads();
  }
  #pragma unroll
  for (int mt=0;mt<4;++mt)
    #pragma unroll
    for (int r=0;r<4;++r) {
      float v = rs[mt][r];
      v += __shfl_xor(v, 1); v += __shfl_xor(v, 2);
      v += __shfl_xor(v, 4); v += __shfl_xor(v, 8);
      rs[mt][r] = v;
    }
  if (MODE==0) {
    float* fb = fpart + (((size_t)bh*NSLICE + tile)*NM)*65;
    #pragma unroll
    for (int mt=0;mt<4;++mt)
      #pragma unroll
      for (int r=0;r<4;++r) {
        int row = wid*64 + mt*16 + lg*4 + r;
        float* fr = fb + (size_t)row*65;
        #pragma unroll
        for (int dt=0;dt<4;++dt) fr[dt*16+lm] = oacc[mt][dt][r];
        if (lm==0) fr[64] = rs[mt][r];
      }
  } else {
    const int b_ = bh>>3, h_ = bh&7;
    #pragma unroll
    for (int mt=0;mt<4;++mt)
      #pragma unroll
      for (int r=0;r<4;++r) {
        float inv = 1.0f/rs[mt][r];
        int n = tile*256 + wid*64 + mt*16 + lg*4 + r;
        bf16u* orow = outb + ((size_t)b_*NSEQ + n)*DIMC + h_*DH;
        #pragma unroll
        for (int dt=0;dt<4;++dt)
          orow[dt*16+lm] = f2b(oacc[mt][dt][r]*inv);
      }
  }
}

// combine -> w1T fp32 [bh][64][256]
__global__ __launch_bounds__(256) void k_attn3v_combine(
    const float* __restrict__ fpart, float* __restrict__ w1T) {
  int gi = blockIdx.x*4 + (threadIdx.x>>6);
  int d = threadIdx.x & 63;
  int bh = gi >> 8, i = gi & 255;
  float accd = 0, ssum = 0;
  #pragma unroll
  for (int s = 0; s < NSLICE; ++s) {
    const float* fp = fpart + (((size_t)bh*NSLICE + s)*NM + i)*65;
    accd += fp[d];
    ssum += fp[64];
  }
  w1T[((size_t)bh*64 + d)*256 + i] = accd / ssum;
}

// ---------------- w2T[bh][64][256] = w1T @ z^T  (split-A fp32 w1T, bf16 z)
__global__ __launch_bounds__(256) void k_w2nat(
    const float* __restrict__ w1T, const bf16u* __restrict__ zb,
    bf16u* __restrict__ w2T) {
  __shared__ short Ah[64][36], Al[64][36], Bh[64][36];
  const int bh = blockIdx.y;
  const int n0 = blockIdx.x*64;
  const size_t a0 = (size_t)bh*64*256;
  const size_t s0 = (size_t)bh<<16;
  const int t = threadIdx.x;
  const int wid = t>>6, l = t&63, lm = l&15, lg = l>>4;
  const int wc = wid*16;
  f32x4 acc[4];
  #pragma unroll
  for (int i=0;i<4;++i) acc[i] = (f32x4){0,0,0,0};
  for (int k0=0; k0<256; k0+=32) {
    #pragma unroll
    for (int i=0;i<2;++i) {
      int idx = t + i*256;
      int row = idx>>3, kc = (idx&7)<<2;
      float4 v = *(const float4*)(w1T + a0 + (size_t)row*256 + k0+kc);
      ushort4 hh, ll;
      splt(v.x, hh.x, ll.x); splt(v.y, hh.y, ll.y);
      splt(v.z, hh.z, ll.z); splt(v.w, hh.w, ll.w);
      *(ushort4*)&Ah[row][kc] = hh; *(ushort4*)&Al[row][kc] = ll;
    }
    {
      int row = t>>2, ch = (t&3)<<3;
      *(uint4*)&Bh[row][ch] = *(const uint4*)(zb + s0 + (size_t)(n0+row)*256 + k0+ch);
    }
    __syncthreads();
    short8 sh = *(const short8*)&Bh[wc+lm][lg*8];
    #pragma unroll
    for (int mt=0;mt<4;++mt) {
      short8 ah = *(const short8*)&Ah[mt*16+lm][lg*8];
      short8 al = *(const short8*)&Al[mt*16+lm][lg*8];
      acc[mt] = MFMA16(ah, sh, acc[mt]);
      acc[mt] = MFMA16(al, sh, acc[mt]);
    }
    __syncthreads();
  }
  #pragma unroll
  for (int mt=0;mt<4;++mt)
    #pragma unroll
    for (int r=0;r<4;++r) {
      int gm = mt*16 + lg*4 + r;
      w2T[a0 + (size_t)gm*256 + n0 + wc + lm] = f2b(acc[mt][r]);
    }
}

// ---------------- depthwise conv residual from vT, LDS-transposed staging
__global__ __launch_bounds__(256) void k_conv_add(
    const bf16u* __restrict__ vt, const float* __restrict__ wc, bf16u* __restrict__ outb) {
  __shared__ short Vs[288][72];
  __shared__ float Wsh[40];
  const int bh = blockIdx.y, n0 = blockIdx.x*256;
  const int b_ = bh>>3, h_ = bh&7;
  const int t = threadIdx.x;
  if (t < KW) Wsh[t] = wc[h_*KW + t];
  const bf16u* vrow = vt + (size_t)bh*DH*NSEQ;
  {
    int d = t&63, seg = t>>6;
    #pragma unroll
    for (int u=0; u<9; ++u) {
      int nl = seg*72 + u*8;
      int gn = n0 - 16 + nl;
      bf16u e8[8];
      if (gn >= 0 && gn + 8 <= NSEQ) {
        *(uint4*)e8 = *(const uint4*)(vrow + (size_t)d*NSEQ + gn);
      } else {
        #pragma unroll
        for (int e=0;e<8;++e) {
          int g = gn + e;
          e8[e] = (g>=0 && g<NSEQ) ? vrow[(size_t)d*NSEQ + g] : (bf16u)0;
        }
      }
      #pragma unroll
      for (int e=0;e<8;++e) Vs[nl+e][d] = e8[e];
    }
  }
  __syncthreads();
  const int d = t&63, q = t>>6;
  #pragma unroll
  for (int c2=0;c2<4;++c2) {
    int nb = q*64 + c2*16;
    float wv[48];
    #pragma unroll
    for (int i=0;i<48;++i) wv[i] = b2f(Vs[nb+i][d]);
    #pragma unroll
    for (int e=0;e<16;++e) {
      float s = 0;
      #pragma unroll
      for (int k=0;k<KW;++k) s = fmaf(wv[e+k], Wsh[k], s);
      size_t oi = ((size_t)b_*NSEQ + n0 + nb + e)*DIMC + h_*DH + d;
      outb[oi] = f2b(b2f(outb[oi]) + s);
    }
  }
}

extern "C" void kernel_launch(void* const* d_in, const int* in_sizes, int n_in,
                              void* d_out, int out_size, void* d_ws, size_t ws_size,
                              hipStream_t stream) {
  (void)in_sizes; (void)n_in;
  const float* x      = (const float*)d_in[0];
  const float* w_qkv  = (const float*)d_in[1];
  const float* w_out  = (const float*)d_in[2];
  const float* b_out  = (const float*)d_in[3];
  const float* w_conv = (const float*)d_in[4];
  float* out = (float*)d_out;

  const size_t QKV_E = (size_t)BHN*NSEQ*DH;   // 16,777,216
  const size_t LM_E  = (size_t)BHN*NM*DH;     // 524,288
  const size_t MM_E  = (size_t)BHN*NM*NM;     // 2,097,152
  const size_t PLSZ  = MM_E*2;                // one bf16 plane = 4 MiB

  char* p = (char*)d_ws;
  char* nsb   = p;          p += 9*PLSZ;      // 36 MiB: xb | NS planes + a2f | fpart (34.1)
  bf16u* zcb  = (bf16u*)p;  p += PLSZ;        // z plane OUTSIDE fpart alias range
  bf16u* qb    = (bf16u*)p; p += QKV_E*2;
  bf16u* kb    = (bf16u*)p; p += QKV_E*2;     // (-> outb)
  bf16u* vT    = (bf16u*)p; p += QKV_E*2;
  bf16u* wqkvT = (bf16u*)p; p += (size_t)DIMC*3*DIMC*2;
  bf16u* woutT = (bf16u*)p; p += (size_t)DIMC*DIMC*2;
  float* ql    = (float*)p; p += LM_E*4;
  float* klm   = (float*)p; p += LM_E*4;
  bf16u* qlb   = (bf16u*)p; p += LM_E*2;
  bf16u* klmb  = (bf16u*)p; p += LM_E*2;
  float* w1T   = (float*)p; p += LM_E*4;
  bf16u* w2T   = (bf16u*)p; p += LM_E*2;
  unsigned* scal = (unsigned*)p; p += 256;
  size_t need = (size_t)(p - (char*)d_ws);

  if (ws_size < need) {
    k_fill<<<(out_size + 255)/256, 256, 0, stream>>>(out, out_size, 12345.0f);
    return;
  }

  // plane map (each 4 MiB):
  bf16u* a2b  = (bf16u*)(nsb + 0*PLSZ);   // -> c1b after w0
  bf16u* s1b  = (bf16u*)(nsb + 1*PLSZ);
  bf16u* cmb  = (bf16u*)(nsb + 2*PLSZ);
  bf16u* wb   = (bf16u*)(nsb + 3*PLSZ);
  float* a2f  = (float*)(nsb + 4*PLSZ);   // fp32 a2 at planes 4-5 (8 MiB)
  float* fpart = (float*)nsb;             // 34.1 MiB after NS done
  bf16u* c1b = a2b;
  bf16u* xb  = (bf16u*)nsb;               // x bf16 (32 MiB), dead before a2f written

  // 1. converts
  c_prep<<<12288, 256, 0, stream>>>(x, w_qkv, w_out, xb, wqkvT, woutT);
  // 2. qkv projection (MFMA, XCD-chunked swizzle)
  k_mgemm<0><<<3072, 256, 0, stream>>>(xb, wqkvT, DIMC, 12, qb, kb, vT, nullptr, nullptr);
  // 3. landmarks
  k_landmarks<<<(BHN*NM)/4, 256, 0, stream>>>(qb, kb, ql, klm, qlb, klmb);
  // 4. attn2 = softmax(ql@klm^T)
  k_qlk_exp<<<dim3(8, BHN), 256, 0, stream>>>(ql, klm, a2f, DH);
  k_rowsm<<<BHN*NM/4, 256, 0, stream>>>(a2f, scal);
  // 5. pinv init
  k_pinv_reduce<<<BHN, 256, 0, stream>>>(a2f, scal);
  k_init_b<<<dim3(16, BHN), 256, 0, stream>>>(a2f, scal, a2b, zcb);
  k_ns<0><<<dim3(8, BHN, 1), 256, 0, stream>>>(
      a2b, nullptr, a2b, nullptr, nullptr, wb, nullptr, nullptr, scal);
  // 6. Newton-Schulz (bf16, 2 launches/iter, in-place w,z)
  for (int it = 0; it < NITER; ++it) {
    k_ns<1><<<dim3(8, BHN, 2), 256, 0, stream>>>(
        wb, zcb, wb, wb, nullptr, s1b, c1b, cmb, nullptr);
    k_ns<2><<<dim3(8, BHN, (it==NITER-1)?1:2), 256, 0, stream>>>(
        s1b, c1b, cmb, wb, zcb, wb, zcb, nullptr, nullptr);
  }
  // 7. w1 = softmax(ql@k^T)@v (MFMA flash, 16 slices) -> w1T
  k_flash<0><<<dim3(NSLICE, BHN), 256, 0, stream>>>(qlb, kb, vT, fpart, nullptr);
  k_attn3v_combine<<<(BHN*NM)/4, 256, 0, stream>>>(fpart, w1T);
  // 8. w2T = w1T @ z^T
  k_w2nat<<<dim3(4, BHN), 256, 0, stream>>>(w1T, zcb, w2T);
  // 9. attn1 @ w2 -> outb (MFMA flash)
  bf16u* outb = kb;
  k_flash<1><<<dim3(NSEQ/256, BHN), 256, 0, stream>>>(qb, klmb, w2T, nullptr, outb);
  // 10. conv residual
  k_conv_add<<<dim3(NSEQ/256, BHN), 256, 0, stream>>>(vT, w_conv, outb);
  // 11. output projection
  k_mgemm<1><<<1024, 256, 0, stream>>>(outb, woutT, DIMC, 4, nullptr, nullptr, nullptr, b_out, out);
}